// Round 7
// baseline (1559.628 us; speedup 1.0000x reference)
//
#include <hip/hip_runtime.h>
#include <hip/hip_bf16.h>

#define LNUM 128
#define NNODES 30000
#define NEDGES 150000
#define NSTEPS 5

// NOTE (r17 discovery): d_out is FLOAT32 (reference is pure jnp.float32).
// Split-f16 numerics: x = hi + lo/2048 -> 3 MFMAs per frag pair, ~f32 accuracy.
// r6 post-mortem: dbuf null (180==181); r1/r5/r6 converge ~180us; node kernel
// (no atomics/gathers) same per-FLOP pace -> core-loop latency-bound, LDS-read
// is busiest pipe (~26%). r7: ILP x2 — 32 edges/wave (two A-frags), 128-thr
// blocks, weight LDS reads shared by both frags (6 MFMAs per wh/wl pair).
// Single-buffer weights (r5 pattern, bit-exact twice-verified formulas).

typedef _Float16 f16;
typedef __attribute__((ext_vector_type(8))) _Float16 f16x8;
typedef __attribute__((ext_vector_type(4))) float f32x4;

__device__ __forceinline__ void glds16(const void* g, void* l) {
    __builtin_amdgcn_global_load_lds(
        (const __attribute__((address_space(1))) void*)g,
        (__attribute__((address_space(3))) void*)l, 16, 0, 0);
}

__device__ __forceinline__ uint32_t pk2(f16 a, f16 b) {
    union { f16 h[2]; uint32_t u; } x; x.h[0] = a; x.h[1] = b; return x.u;
}

// ---------------------------------------------------------------------------
// Legacy VALU MLP core: still used by the (small) encode_nodes kernel.
// ---------------------------------------------------------------------------
template<int ROWS, int K, int KP>
__device__ __forceinline__ void mlp_apply(
    const float* __restrict__ xs, float* __restrict__ hv,
    float* __restrict__ mu_s, float* __restrict__ rs_s,
    const float* __restrict__ W1, const float* __restrict__ b1,
    const float* __restrict__ W2, const float* __restrict__ b2,
    const float* __restrict__ g,  const float* __restrict__ be,
    float out[ROWS])
{
    const int t = threadIdx.x;
    float acc[ROWS];
    {
        const float bb = b1[t];
        #pragma unroll
        for (int r = 0; r < ROWS; r++) acc[r] = bb;
    }
    int k = 0;
    for (; k + 4 <= K; k += 4) {
        const float w0 = W1[(k + 0) * LNUM + t];
        const float w1 = W1[(k + 1) * LNUM + t];
        const float w2 = W1[(k + 2) * LNUM + t];
        const float w3 = W1[(k + 3) * LNUM + t];
        #pragma unroll
        for (int r = 0; r < ROWS; r++) {
            const float4 x = *(const float4*)(xs + r * KP + k);
            acc[r] = fmaf(x.x, w0, acc[r]);
            acc[r] = fmaf(x.y, w1, acc[r]);
            acc[r] = fmaf(x.z, w2, acc[r]);
            acc[r] = fmaf(x.w, w3, acc[r]);
        }
    }
    for (; k < K; ++k) {
        const float w = W1[k * LNUM + t];
        #pragma unroll
        for (int r = 0; r < ROWS; r++) acc[r] = fmaf(xs[r * KP + k], w, acc[r]);
    }
    #pragma unroll
    for (int r = 0; r < ROWS; r++) hv[r * LNUM + t] = fmaxf(acc[r], 0.f);
    __syncthreads();
    {
        const float bb = b2[t];
        #pragma unroll
        for (int r = 0; r < ROWS; r++) acc[r] = bb;
    }
    for (int k2 = 0; k2 < LNUM; k2 += 4) {
        const float w0 = W2[(k2 + 0) * LNUM + t];
        const float w1 = W2[(k2 + 1) * LNUM + t];
        const float w2 = W2[(k2 + 2) * LNUM + t];
        const float w3 = W2[(k2 + 3) * LNUM + t];
        #pragma unroll
        for (int r = 0; r < ROWS; r++) {
            const float4 x = *(const float4*)(hv + r * LNUM + k2);
            acc[r] = fmaf(x.x, w0, acc[r]);
            acc[r] = fmaf(x.y, w1, acc[r]);
            acc[r] = fmaf(x.z, w2, acc[r]);
            acc[r] = fmaf(x.w, w3, acc[r]);
        }
    }
    __syncthreads();
    #pragma unroll
    for (int r = 0; r < ROWS; r++) hv[r * LNUM + t] = fmaxf(acc[r], 0.f);
    __syncthreads();
    if (t < ROWS) {
        float s = 0.f, s2 = 0.f;
        for (int kk = 0; kk < LNUM; kk++) {
            const float v = hv[t * LNUM + kk];
            s += v; s2 += v * v;
        }
        const float m = s * (1.0f / LNUM);
        mu_s[t] = m;
        rs_s[t] = rsqrtf(fmaxf(s2 * (1.0f / LNUM) - m * m, 0.f) + 1e-5f);
    }
    __syncthreads();
    const float gg = g[t], bbe = be[t];
    #pragma unroll
    for (int r = 0; r < ROWS; r++)
        out[r] = fmaf(gg * (hv[r * LNUM + t] - mu_s[r]), rs_s[r], bbe);
}

__global__ __launch_bounds__(128) void encode_nodes_k(
    const float* __restrict__ u, const float* __restrict__ load_,
    const float* __restrict__ ntype,
    const float* __restrict__ W1, const float* __restrict__ b1,
    const float* __restrict__ W2, const float* __restrict__ b2,
    const float* __restrict__ g,  const float* __restrict__ be,
    float* __restrict__ nl)
{
    constexpr int ROWS = 4, K = 12, KP = 12;
    __shared__ __align__(16) float xs[ROWS * KP];
    __shared__ __align__(16) float hv[ROWS * LNUM];
    __shared__ float mu_s[ROWS], rs_s[ROWS];
    const int t = threadIdx.x;
    const int base = blockIdx.x * ROWS;
    if (t < ROWS * K) {
        const int r = t / K, k = t % K;
        const int n = base + r;
        float v;
        if (k < 2)      v = u[n * 2 + k];
        else if (k < 3) v = load_[n];
        else            v = ntype[n * 9 + (k - 3)];
        xs[r * KP + k] = v;
    }
    __syncthreads();
    float out[ROWS];
    mlp_apply<ROWS, K, KP>(xs, hv, mu_s, rs_s, W1, b1, W2, b2, g, be, out);
    #pragma unroll
    for (int r = 0; r < ROWS; r++) nl[(base + r) * LNUM + t] = out[r];
}

// ---------------------------------------------------------------------------
// Weight prep: f32 [S][K][128] -> f16 hi/lo tables transposed to [S][128][K].
// ---------------------------------------------------------------------------
#define PE1 245760   // 5*384*128 (edge W1)
#define PE2 81920    // 5*128*128 (edge W2)
#define PN1 163840   // 5*256*128 (node W1)
#define PN2 81920    // 5*128*128 (node W2)
#define PQ1 4096     // 128*32    (enc-edge W1, k-padded)
#define PQ2 16384    // 128*128   (enc-edge W2)
#define PTOT (PE1+PE2+PN1+PN2+PQ1+PQ2)

__global__ __launch_bounds__(256) void prep_w_all_k(
    const float* __restrict__ eW1, const float* __restrict__ eW2,
    const float* __restrict__ nW1, const float* __restrict__ nW2,
    const float* __restrict__ qW1, const float* __restrict__ qW2,
    f16* __restrict__ out)
{
    int j = blockIdx.x * 256 + threadIdx.x;
    if (j >= PTOT) return;
    const float* W; int K, kreal; f16 *hi, *lo; f16* p = out;
    if (j < PE1) { W = eW1; K = 384; kreal = 384; hi = p; lo = p + PE1; }
    else { p += 2 * PE1; j -= PE1;
    if (j < PE2) { W = eW2; K = 128; kreal = 128; hi = p; lo = p + PE2; }
    else { p += 2 * PE2; j -= PE2;
    if (j < PN1) { W = nW1; K = 256; kreal = 256; hi = p; lo = p + PN1; }
    else { p += 2 * PN1; j -= PN1;
    if (j < PN2) { W = nW2; K = 128; kreal = 128; hi = p; lo = p + PN2; }
    else { p += 2 * PN2; j -= PN2;
    if (j < PQ1) { W = qW1; K = 32;  kreal = 5;   hi = p; lo = p + PQ1; }
    else { p += 2 * PQ1; j -= PQ1;
         { W = qW2; K = 128; kreal = 128; hi = p; lo = p + PQ2; } } } } } }
    const int k = j % K;
    const int rem = j / K;
    const int n = rem & 127;
    const int s = rem >> 7;
    const float v = (k < kreal) ? W[((size_t)s * kreal + k) * 128 + n] : 0.f;
    const f16 h = (f16)v;
    hi[j] = h;
    lo[j] = (f16)((v - (float)h) * 2048.f);
}

// ---------------------------------------------------------------------------
// MFMA MLP, 2 waves x 32 edges each (two A-frags), 64 rows/block, 128 thr.
// Weights: ONE 32-wide K chunk (hi+lo, 16KB) staged per iter (r5-verified
// glds16 + XOR swizzle, 2 barriers/chunk). Each wh/wl LDS pair feeds SIX
// MFMAs (3 per frag) -> LDS-read bytes per edge halved vs r5/r6.
// Data: per-lane reg gather per frag, prefetched 1 chunk ahead.
// Layer1->2 transpose via wave-private packed Yp (rows [w*32, w*32+32)).
// D layout (verified): edge = lg*4+reg (+frag base), feature = mf*16+lr.
// MODE: 0 = edge block, 1 = node block, 2 = edge encoder.
// ---------------------------------------------------------------------------
template<int MODE, int NCH1, int K1S>
__global__ __launch_bounds__(128) void mfma_mlp_k(
    const float* __restrict__ in0, const float* __restrict__ in1,
    float* __restrict__ io, float* __restrict__ aggr,
    const int* __restrict__ senders, const int* __restrict__ receivers,
    const f16* __restrict__ W1h, const f16* __restrict__ W1l, const float* __restrict__ b1,
    const f16* __restrict__ W2h, const f16* __restrict__ W2l, const float* __restrict__ b2,
    const float* __restrict__ gam, const float* __restrict__ bet,
    int nrows)
{
    __shared__ __align__(16) f16 WH[4096];            // [128][32] swizzled, 8KB
    __shared__ __align__(16) f16 WL[4096];            // 8KB
    __shared__ __align__(16) uint32_t Yp[64 * 132];   // packed hi|lo, 33.8KB

    const int t  = threadIdx.x;       // 0..127
    const int w  = t >> 6;            // wave 0..1
    const int l  = t & 63;
    const int lr = l & 15;
    const int lg = l >> 4;
    const int swz = lg ^ ((lr >> 1) & 3);
    const int base = blockIdx.x * 64;

    // frag f: gather row (A-layout) = base + w*32 + f*16 + lr
    int egc[2], sv[2], rv[2];
    #pragma unroll
    for (int f = 0; f < 2; f++) {
        const int eg = base + w * 32 + f * 16 + lr;
        egc[f] = min(eg, nrows - 1);
        sv[f] = 0; rv[f] = 0;
        if constexpr (MODE != 1) { sv[f] = senders[egc[f]]; rv[f] = receivers[egc[f]]; }
    }

    float feat[2][8];
    if constexpr (MODE == 2) {
        #pragma unroll
        for (int f = 0; f < 2; f++) {
            const float ax = in0[sv[f] * 2], ay = in0[sv[f] * 2 + 1];
            const float bx = in0[rv[f] * 2], by = in0[rv[f] * 2 + 1];
            const float rx = ax - bx, ry = ay - by;
            feat[f][0] = rx; feat[f][1] = ry;
            feat[f][2] = sqrtf(rx * rx + ry * ry);
            feat[f][3] = in1[sv[f] * 2] - in1[rv[f] * 2];
            feat[f][4] = in1[sv[f] * 2 + 1] - in1[rv[f] * 2 + 1];
            feat[f][5] = 0.f; feat[f][6] = 0.f; feat[f][7] = 0.f;
        }
    }

    // r5-verified cooperative stage of one 32-wide K chunk (hi+lo).
    // 128 threads: c = 4*w + i covers all 8 x 1KB columns.
    auto stage = [&](const f16* __restrict__ Wh, const f16* __restrict__ Wl,
                     const int kst, const int kc) {
        #pragma unroll
        for (int i = 0; i < 4; i++) {
            const int c = 4 * w + i;
            const int ophys = c * 1024 + l * 16;
            const int olog  = ophys ^ (((ophys >> 7) & 3) << 4);
            const int row   = olog >> 6;
            const int slot  = (olog >> 4) & 3;
            glds16(Wh + (size_t)row * kst + kc * 32 + slot * 8, (char*)WH + c * 1024);
            glds16(Wl + (size_t)row * kst + kc * 32 + slot * 8, (char*)WL + c * 1024);
        }
    };

    // per-lane data gather for one frag (raw f32, 8 elems).
    auto gather = [&](int kc, int svf, int rvf, int egf, const float* ft,
                      float xv[8]) {
        if constexpr (MODE == 2) {
            #pragma unroll
            for (int j = 0; j < 8; j++) xv[j] = (lg == 0) ? ft[j] : 0.f;
        } else {
            const float* src;
            if constexpr (MODE == 0) {
                if (kc < 4)      src = in0 + (size_t)svf * 128 + kc * 32 + lg * 8;
                else if (kc < 8) src = in0 + (size_t)rvf * 128 + (kc - 4) * 32 + lg * 8;
                else             src = in1 + (size_t)egf * 128 + (kc - 8) * 32 + lg * 8;
            } else {
                if (kc < 4) src = in0 + (size_t)egf * 128 + kc * 32 + lg * 8;
                else        src = in1 + (size_t)egf * 128 + (kc - 4) * 32 + lg * 8;
            }
            const float4 x0 = *(const float4*)src;
            const float4 x1 = *(const float4*)(src + 4);
            xv[0] = x0.x; xv[1] = x0.y; xv[2] = x0.z; xv[3] = x0.w;
            xv[4] = x1.x; xv[5] = x1.y; xv[6] = x1.z; xv[7] = x1.w;
        }
    };

    auto cvt8 = [&](const float xv[8], f16x8& H, f16x8& L) {
        union { f16 h[8]; f16x8 v; } uh, ul;
        #pragma unroll
        for (int j = 0; j < 8; j++) {
            const f16 h = (f16)xv[j];
            uh.h[j] = h;
            ul.h[j] = (f16)((xv[j] - (float)h) * 2048.f);
        }
        H = uh.v; L = ul.v;
    };

    const f32x4 zero4 = {0.f, 0.f, 0.f, 0.f};
    f32x4 aH[2][8], aL[2][8];
    #pragma unroll
    for (int f = 0; f < 2; f++)
        #pragma unroll
        for (int mf = 0; mf < 8; mf++) { aH[f][mf] = zero4; aL[f][mf] = zero4; }

    float xn0[8], xn1[8];
    gather(0, sv[0], rv[0], egc[0], feat[0], xn0);
    gather(0, sv[1], rv[1], egc[1], feat[1], xn1);

    // ---------------- layer 1 (r5 2-barrier pattern) ----------------
    for (int kc = 0; kc < NCH1; ++kc) {
        __syncthreads();                  // prior readers of WH/WL done
        stage(W1h, W1l, K1S, kc);
        f16x8 XH[2], XL[2];
        cvt8(xn0, XH[0], XL[0]);
        cvt8(xn1, XH[1], XL[1]);
        __syncthreads();                  // weights staged (vmcnt drained)
        if (kc + 1 < NCH1) {              // prefetch next data chunk
            gather(kc + 1, sv[0], rv[0], egc[0], feat[0], xn0);
            gather(kc + 1, sv[1], rv[1], egc[1], feat[1], xn1);
        }
        #pragma unroll
        for (int mf = 0; mf < 8; mf++) {
            const int off = (mf * 16 + lr) * 64 + (swz << 4);
            const f16x8 wh = *(const f16x8*)((const char*)WH + off);
            const f16x8 wl = *(const f16x8*)((const char*)WL + off);
            #pragma unroll
            for (int f = 0; f < 2; f++) {
                aH[f][mf] = __builtin_amdgcn_mfma_f32_16x16x32_f16(XH[f], wh, aH[f][mf], 0, 0, 0);
                aL[f][mf] = __builtin_amdgcn_mfma_f32_16x16x32_f16(XL[f], wh, aL[f][mf], 0, 0, 0);
                aL[f][mf] = __builtin_amdgcn_mfma_f32_16x16x32_f16(XH[f], wl, aL[f][mf], 0, 0, 0);
            }
        }
    }

    // layer-1 epilogue: bias+relu+split -> packed Y, wave-private rows.
    #pragma unroll
    for (int f = 0; f < 2; f++) {
        #pragma unroll
        for (int mf = 0; mf < 8; mf++) {
            const float bb1 = b1[mf * 16 + lr];
            #pragma unroll
            for (int reg = 0; reg < 4; reg++) {
                float v = aH[f][mf][reg] + aL[f][mf][reg] * (1.f / 2048.f) + bb1;
                v = fmaxf(v, 0.f);
                const f16 h = (f16)v;
                const f16 lo = (f16)((v - (float)h) * 2048.f);
                Yp[(w * 32 + f * 16 + lg * 4 + reg) * 132 + mf * 16 + lr] = pk2(h, lo);
            }
            aH[f][mf] = zero4; aL[f][mf] = zero4;
        }
    }

    // ---------------- layer 2 ----------------
    for (int kc = 0; kc < 4; ++kc) {
        __syncthreads();
        stage(W2h, W2l, 128, kc);
        f16x8 XH[2], XL[2];
        #pragma unroll
        for (int f = 0; f < 2; f++) {
            const uint32_t* yrow = Yp + (w * 32 + f * 16 + lr) * 132 + kc * 32 + lg * 8;
            union { uint32_t u[8]; } Q;
            *(uint4*)&Q.u[0] = *(const uint4*)(yrow);
            *(uint4*)&Q.u[4] = *(const uint4*)(yrow + 4);
            union { f16 h[8]; f16x8 v; } uh, ul;
            #pragma unroll
            for (int j = 0; j < 8; j++) {
                union { uint32_t u; f16 h[2]; } c; c.u = Q.u[j];
                uh.h[j] = c.h[0]; ul.h[j] = c.h[1];
            }
            XH[f] = uh.v; XL[f] = ul.v;
        }
        __syncthreads();
        #pragma unroll
        for (int mf = 0; mf < 8; mf++) {
            const int off = (mf * 16 + lr) * 64 + (swz << 4);
            const f16x8 wh = *(const f16x8*)((const char*)WH + off);
            const f16x8 wl = *(const f16x8*)((const char*)WL + off);
            #pragma unroll
            for (int f = 0; f < 2; f++) {
                aH[f][mf] = __builtin_amdgcn_mfma_f32_16x16x32_f16(XH[f], wh, aH[f][mf], 0, 0, 0);
                aL[f][mf] = __builtin_amdgcn_mfma_f32_16x16x32_f16(XL[f], wh, aL[f][mf], 0, 0, 0);
                aL[f][mf] = __builtin_amdgcn_mfma_f32_16x16x32_f16(XH[f], wl, aL[f][mf], 0, 0, 0);
            }
        }
    }

    // layer-2 epilogue (verified pattern), per frag sequentially.
    float gg[8], b8[8];
    #pragma unroll
    for (int mf = 0; mf < 8; mf++) {
        gg[mf] = gam[mf * 16 + lr];
        b8[mf] = bet[mf * 16 + lr];
    }

    #pragma unroll
    for (int f = 0; f < 2; f++) {
        float vv[8][4];
        float s1[4] = {0, 0, 0, 0}, s2[4] = {0, 0, 0, 0};
        #pragma unroll
        for (int mf = 0; mf < 8; mf++) {
            const float bb2 = b2[mf * 16 + lr];
            #pragma unroll
            for (int reg = 0; reg < 4; reg++) {
                float v = aH[f][mf][reg] + aL[f][mf][reg] * (1.f / 2048.f) + bb2;
                v = fmaxf(v, 0.f);
                vv[mf][reg] = v;
                s1[reg] += v; s2[reg] += v * v;
            }
        }
        #pragma unroll
        for (int m = 1; m < 16; m <<= 1) {
            #pragma unroll
            for (int reg = 0; reg < 4; reg++) {
                s1[reg] += __shfl_xor(s1[reg], m);
                s2[reg] += __shfl_xor(s2[reg], m);
            }
        }
        #pragma unroll
        for (int reg = 0; reg < 4; reg++) {
            const float mu = s1[reg] * (1.f / 128.f);
            const float rs = rsqrtf(fmaxf(s2[reg] * (1.f / 128.f) - mu * mu, 0.f) + 1e-5f);
            const int idx = base + w * 32 + f * 16 + lg * 4 + reg;
            if (idx < nrows) {
                if constexpr (MODE == 0) {
                    const int rc = receivers[idx];
                    #pragma unroll
                    for (int mf = 0; mf < 8; mf++) {
                        const float o = gg[mf] * (vv[mf][reg] - mu) * rs + b8[mf];
                        atomicAdd(&aggr[(size_t)rc * 128 + mf * 16 + lr], o); // segsum
                        io[(size_t)idx * 128 + mf * 16 + lr] += o;            // el res
                    }
                } else if constexpr (MODE == 1) {
                    #pragma unroll
                    for (int mf = 0; mf < 8; mf++) {
                        const float o = gg[mf] * (vv[mf][reg] - mu) * rs + b8[mf];
                        io[(size_t)idx * 128 + mf * 16 + lr] += o;            // nl res
                    }
                } else {
                    #pragma unroll
                    for (int mf = 0; mf < 8; mf++) {
                        const float o = gg[mf] * (vv[mf][reg] - mu) * rs + b8[mf];
                        io[(size_t)idx * 128 + mf * 16 + lr] = o;             // el enc
                    }
                }
            }
        }
    }
}

// Decoder -> FLOAT32 output, layout [TW, N, TD].
__global__ __launch_bounds__(128) void decode_k(
    const float* __restrict__ nl,
    const float* __restrict__ W1, const float* __restrict__ b1,
    const float* __restrict__ W2, const float* __restrict__ b2,
    float* __restrict__ out)
{
    constexpr int NPB = 16;
    __shared__ __align__(16) float xs[NPB * LNUM];
    __shared__ float hh[NPB * 8];
    const int t = threadIdx.x;
    const int base = blockIdx.x * NPB;
    for (int r = 0; r < NPB; r++) xs[r * LNUM + t] = nl[(base + r) * LNUM + t];
    __syncthreads();
    {
        const int node = t >> 3, j = t & 7;
        float a = b1[j];
        for (int k = 0; k < LNUM; k++) a = fmaf(xs[node * LNUM + k], W1[k * 8 + j], a);
        hh[node * 8 + j] = a / (1.f + expf(-a));
    }
    __syncthreads();
    for (int idx = t; idx < NPB * 10; idx += 128) {
        const int node = idx / 10, c = idx % 10;
        float a = b2[c];
        #pragma unroll
        for (int j = 0; j < 8; j++) a = fmaf(hh[node * 8 + j], W2[j * 10 + c], a);
        const int tt = c >> 1, d = c & 1;
        out[(size_t)tt * (NNODES * 2) + (size_t)(base + node) * 2 + d] =
            a * (float)(tt + 1);
    }
}

__global__ __launch_bounds__(256) void zero_k(float* __restrict__ p, int n)
{
    const int i = blockIdx.x * 256 + threadIdx.x;
    if (i < n) p[i] = 0.f;
}

// ---------------------------------------------------------------------------
extern "C" void kernel_launch(void* const* d_in, const int* in_sizes, int n_in,
                              void* d_out, int out_size, void* d_ws, size_t ws_size,
                              hipStream_t stream) {
    const float* F[34];
    for (int i = 0; i < 34; i++) F[i] = (const float*)d_in[i];
    const int* senders   = (const int*)d_in[4];
    const int* receivers = (const int*)d_in[5];

    const size_t nN = (size_t)NNODES * LNUM;
    const size_t nE = (size_t)NEDGES * LNUM;
    float* nl   = (float*)d_ws;
    float* el   = nl + nN;
    float* aggr = el + nE;
    f16* wb = (f16*)(aggr + nN);
    f16 *eW1h = wb,          *eW1l = eW1h + PE1;
    f16 *eW2h = eW1l + PE1,  *eW2l = eW2h + PE2;
    f16 *nW1h = eW2l + PE2,  *nW1l = nW1h + PN1;
    f16 *nW2h = nW1l + PN1,  *nW2l = nW2h + PN2;
    f16 *qW1h = nW2l + PN2,  *qW1l = qW1h + PQ1;
    f16 *qW2h = qW1l + PQ1,  *qW2l = qW2h + PQ2;

    prep_w_all_k<<<(PTOT + 255) / 256, 256, 0, stream>>>(
        F[18], F[20], F[24], F[26], F[12], F[14], wb);

    encode_nodes_k<<<NNODES / 4, 128, 0, stream>>>(
        F[2], F[3], F[1], F[6], F[7], F[8], F[9], F[10], F[11], nl);

    const int egrid = (NEDGES + 63) / 64;   // 2344 blocks of 128 threads
    const int ngrid = (NNODES + 63) / 64;   // 469

    // edge encoder (MFMA, computed features)
    mfma_mlp_k<2, 1, 32><<<egrid, 128, 0, stream>>>(
        F[0], F[2], el, nullptr, senders, receivers,
        qW1h, qW1l, F[13], qW2h, qW2l, F[15], F[16], F[17], NEDGES);

    for (int s = 0; s < NSTEPS; s++) {
        zero_k<<<(NNODES * LNUM + 255) / 256, 256, 0, stream>>>(aggr, NNODES * LNUM);
        mfma_mlp_k<0, 12, 384><<<egrid, 128, 0, stream>>>(
            nl, el, el, aggr, senders, receivers,
            eW1h + (size_t)s * 384 * 128, eW1l + (size_t)s * 384 * 128, F[19] + s * LNUM,
            eW2h + (size_t)s * 128 * 128, eW2l + (size_t)s * 128 * 128, F[21] + s * LNUM,
            F[22] + s * LNUM, F[23] + s * LNUM, NEDGES);
        mfma_mlp_k<1, 8, 256><<<ngrid, 128, 0, stream>>>(
            nl, aggr, nl, nullptr, nullptr, nullptr,
            nW1h + (size_t)s * 256 * 128, nW1l + (size_t)s * 256 * 128, F[25] + s * LNUM,
            nW2h + (size_t)s * 128 * 128, nW2l + (size_t)s * 128 * 128, F[27] + s * LNUM,
            F[28] + s * LNUM, F[29] + s * LNUM, NNODES);
    }

    decode_k<<<NNODES / 16, 128, 0, stream>>>(
        nl, F[30], F[31], F[32], F[33], (float*)d_out);
}

// Round 8
// 1551.961 us; speedup vs baseline: 1.0049x; 1.0049x over previous
//
#include <hip/hip_runtime.h>
#include <hip/hip_bf16.h>

#define LNUM 128
#define NNODES 30000
#define NEDGES 150000
#define NSTEPS 5

// NOTE (r17 discovery): d_out is FLOAT32 (reference is pure jnp.float32).
// Split-f16 numerics: x = hi + lo/2048 -> 3 MFMAs per frag pair, ~f32 accuracy.
// r7 post-mortem: 128-thr blocks halved waves/CU (LDS/block unchanged) ->
// occupancy 10.5%, regression. r8: 256-thr / 4-wave / 2-frag = 128 edges per
// block (r7's ILP at r5's block shape). Y buffer f16-only (hi) to keep LDS
// ~51.5KB (3 blocks/CU): layer-2 input quantized f16 (~1e-3/MLP, bounded),
// saves 1/3 of layer-2 MFMAs + half Y ds_read. Layer-1 keeps full split.

typedef _Float16 f16;
typedef __attribute__((ext_vector_type(8))) _Float16 f16x8;
typedef __attribute__((ext_vector_type(4))) float f32x4;

__device__ __forceinline__ void glds16(const void* g, void* l) {
    __builtin_amdgcn_global_load_lds(
        (const __attribute__((address_space(1))) void*)g,
        (__attribute__((address_space(3))) void*)l, 16, 0, 0);
}

// ---------------------------------------------------------------------------
// Legacy VALU MLP core: still used by the (small) encode_nodes kernel.
// ---------------------------------------------------------------------------
template<int ROWS, int K, int KP>
__device__ __forceinline__ void mlp_apply(
    const float* __restrict__ xs, float* __restrict__ hv,
    float* __restrict__ mu_s, float* __restrict__ rs_s,
    const float* __restrict__ W1, const float* __restrict__ b1,
    const float* __restrict__ W2, const float* __restrict__ b2,
    const float* __restrict__ g,  const float* __restrict__ be,
    float out[ROWS])
{
    const int t = threadIdx.x;
    float acc[ROWS];
    {
        const float bb = b1[t];
        #pragma unroll
        for (int r = 0; r < ROWS; r++) acc[r] = bb;
    }
    int k = 0;
    for (; k + 4 <= K; k += 4) {
        const float w0 = W1[(k + 0) * LNUM + t];
        const float w1 = W1[(k + 1) * LNUM + t];
        const float w2 = W1[(k + 2) * LNUM + t];
        const float w3 = W1[(k + 3) * LNUM + t];
        #pragma unroll
        for (int r = 0; r < ROWS; r++) {
            const float4 x = *(const float4*)(xs + r * KP + k);
            acc[r] = fmaf(x.x, w0, acc[r]);
            acc[r] = fmaf(x.y, w1, acc[r]);
            acc[r] = fmaf(x.z, w2, acc[r]);
            acc[r] = fmaf(x.w, w3, acc[r]);
        }
    }
    for (; k < K; ++k) {
        const float w = W1[k * LNUM + t];
        #pragma unroll
        for (int r = 0; r < ROWS; r++) acc[r] = fmaf(xs[r * KP + k], w, acc[r]);
    }
    #pragma unroll
    for (int r = 0; r < ROWS; r++) hv[r * LNUM + t] = fmaxf(acc[r], 0.f);
    __syncthreads();
    {
        const float bb = b2[t];
        #pragma unroll
        for (int r = 0; r < ROWS; r++) acc[r] = bb;
    }
    for (int k2 = 0; k2 < LNUM; k2 += 4) {
        const float w0 = W2[(k2 + 0) * LNUM + t];
        const float w1 = W2[(k2 + 1) * LNUM + t];
        const float w2 = W2[(k2 + 2) * LNUM + t];
        const float w3 = W2[(k2 + 3) * LNUM + t];
        #pragma unroll
        for (int r = 0; r < ROWS; r++) {
            const float4 x = *(const float4*)(hv + r * LNUM + k2);
            acc[r] = fmaf(x.x, w0, acc[r]);
            acc[r] = fmaf(x.y, w1, acc[r]);
            acc[r] = fmaf(x.z, w2, acc[r]);
            acc[r] = fmaf(x.w, w3, acc[r]);
        }
    }
    __syncthreads();
    #pragma unroll
    for (int r = 0; r < ROWS; r++) hv[r * LNUM + t] = fmaxf(acc[r], 0.f);
    __syncthreads();
    if (t < ROWS) {
        float s = 0.f, s2 = 0.f;
        for (int kk = 0; kk < LNUM; kk++) {
            const float v = hv[t * LNUM + kk];
            s += v; s2 += v * v;
        }
        const float m = s * (1.0f / LNUM);
        mu_s[t] = m;
        rs_s[t] = rsqrtf(fmaxf(s2 * (1.0f / LNUM) - m * m, 0.f) + 1e-5f);
    }
    __syncthreads();
    const float gg = g[t], bbe = be[t];
    #pragma unroll
    for (int r = 0; r < ROWS; r++)
        out[r] = fmaf(gg * (hv[r * LNUM + t] - mu_s[r]), rs_s[r], bbe);
}

__global__ __launch_bounds__(128) void encode_nodes_k(
    const float* __restrict__ u, const float* __restrict__ load_,
    const float* __restrict__ ntype,
    const float* __restrict__ W1, const float* __restrict__ b1,
    const float* __restrict__ W2, const float* __restrict__ b2,
    const float* __restrict__ g,  const float* __restrict__ be,
    float* __restrict__ nl)
{
    constexpr int ROWS = 4, K = 12, KP = 12;
    __shared__ __align__(16) float xs[ROWS * KP];
    __shared__ __align__(16) float hv[ROWS * LNUM];
    __shared__ float mu_s[ROWS], rs_s[ROWS];
    const int t = threadIdx.x;
    const int base = blockIdx.x * ROWS;
    if (t < ROWS * K) {
        const int r = t / K, k = t % K;
        const int n = base + r;
        float v;
        if (k < 2)      v = u[n * 2 + k];
        else if (k < 3) v = load_[n];
        else            v = ntype[n * 9 + (k - 3)];
        xs[r * KP + k] = v;
    }
    __syncthreads();
    float out[ROWS];
    mlp_apply<ROWS, K, KP>(xs, hv, mu_s, rs_s, W1, b1, W2, b2, g, be, out);
    #pragma unroll
    for (int r = 0; r < ROWS; r++) nl[(base + r) * LNUM + t] = out[r];
}

// ---------------------------------------------------------------------------
// Weight prep: f32 [S][K][128] -> f16 hi/lo tables transposed to [S][128][K].
// ---------------------------------------------------------------------------
#define PE1 245760   // 5*384*128 (edge W1)
#define PE2 81920    // 5*128*128 (edge W2)
#define PN1 163840   // 5*256*128 (node W1)
#define PN2 81920    // 5*128*128 (node W2)
#define PQ1 4096     // 128*32    (enc-edge W1, k-padded)
#define PQ2 16384    // 128*128   (enc-edge W2)
#define PTOT (PE1+PE2+PN1+PN2+PQ1+PQ2)

__global__ __launch_bounds__(256) void prep_w_all_k(
    const float* __restrict__ eW1, const float* __restrict__ eW2,
    const float* __restrict__ nW1, const float* __restrict__ nW2,
    const float* __restrict__ qW1, const float* __restrict__ qW2,
    f16* __restrict__ out)
{
    int j = blockIdx.x * 256 + threadIdx.x;
    if (j >= PTOT) return;
    const float* W; int K, kreal; f16 *hi, *lo; f16* p = out;
    if (j < PE1) { W = eW1; K = 384; kreal = 384; hi = p; lo = p + PE1; }
    else { p += 2 * PE1; j -= PE1;
    if (j < PE2) { W = eW2; K = 128; kreal = 128; hi = p; lo = p + PE2; }
    else { p += 2 * PE2; j -= PE2;
    if (j < PN1) { W = nW1; K = 256; kreal = 256; hi = p; lo = p + PN1; }
    else { p += 2 * PN1; j -= PN1;
    if (j < PN2) { W = nW2; K = 128; kreal = 128; hi = p; lo = p + PN2; }
    else { p += 2 * PN2; j -= PN2;
    if (j < PQ1) { W = qW1; K = 32;  kreal = 5;   hi = p; lo = p + PQ1; }
    else { p += 2 * PQ1; j -= PQ1;
         { W = qW2; K = 128; kreal = 128; hi = p; lo = p + PQ2; } } } } } }
    const int k = j % K;
    const int rem = j / K;
    const int n = rem & 127;
    const int s = rem >> 7;
    const float v = (k < kreal) ? W[((size_t)s * kreal + k) * 128 + n] : 0.f;
    const f16 h = (f16)v;
    hi[j] = h;
    lo[j] = (f16)((v - (float)h) * 2048.f);
}

// ---------------------------------------------------------------------------
// MFMA MLP: 256 thr = 4 waves x 2 frags x 16 edges = 128 rows/block.
// Weights: ONE 32-wide K chunk (hi+lo, 16KB) staged per iter (r5-verified
// glds16 + XOR swizzle, 2 barriers/chunk); each wh/wl LDS pair feeds 6 MFMAs
// (layer 1) / 4 MFMAs (layer 2). Data gathered per-lane per-frag, prefetched
// 1 chunk ahead. Layer1->2 via f16-only Y (wave-private rows, no barrier;
// saves data-lo MFMA + half Y ds_read, costs ~2^-11 rel on h1).
// D layout (verified): row = w*32 + f*16 + lg*4 + reg, feature = mf*16 + lr
// -> epilogue writes/atomics are 16-consecutive-col (full 64B lines).
// MODE: 0 = edge block, 1 = node block, 2 = edge encoder.
// ---------------------------------------------------------------------------
template<int MODE, int NCH1, int K1S>
__global__ __launch_bounds__(256) void mfma_mlp_k(
    const float* __restrict__ in0, const float* __restrict__ in1,
    float* __restrict__ io, float* __restrict__ aggr,
    const int* __restrict__ senders, const int* __restrict__ receivers,
    const f16* __restrict__ W1h, const f16* __restrict__ W1l, const float* __restrict__ b1,
    const f16* __restrict__ W2h, const f16* __restrict__ W2l, const float* __restrict__ b2,
    const float* __restrict__ gam, const float* __restrict__ bet,
    int nrows)
{
    __shared__ __align__(16) f16 WH[4096];          // [128][32] swizzled, 8KB
    __shared__ __align__(16) f16 WL[4096];          // 8KB
    __shared__ __align__(16) unsigned short Yh[128 * 136];  // f16 h1, 34KB

    const int t  = threadIdx.x;       // 0..255
    const int w  = t >> 6;            // wave 0..3
    const int l  = t & 63;
    const int lr = l & 15;
    const int lg = l >> 4;
    const int swz = lg ^ ((lr >> 1) & 3);
    const int base = blockIdx.x * 128;

    // frag f: A-row = base + w*32 + f*16 + lr
    int egc[2], sv[2], rv[2];
    #pragma unroll
    for (int f = 0; f < 2; f++) {
        const int eg = base + w * 32 + f * 16 + lr;
        egc[f] = min(eg, nrows - 1);
        sv[f] = 0; rv[f] = 0;
        if constexpr (MODE != 1) { sv[f] = senders[egc[f]]; rv[f] = receivers[egc[f]]; }
    }

    float feat[2][8];
    if constexpr (MODE == 2) {
        #pragma unroll
        for (int f = 0; f < 2; f++) {
            const float ax = in0[sv[f] * 2], ay = in0[sv[f] * 2 + 1];
            const float bx = in0[rv[f] * 2], by = in0[rv[f] * 2 + 1];
            const float rx = ax - bx, ry = ay - by;
            feat[f][0] = rx; feat[f][1] = ry;
            feat[f][2] = sqrtf(rx * rx + ry * ry);
            feat[f][3] = in1[sv[f] * 2] - in1[rv[f] * 2];
            feat[f][4] = in1[sv[f] * 2 + 1] - in1[rv[f] * 2 + 1];
            feat[f][5] = 0.f; feat[f][6] = 0.f; feat[f][7] = 0.f;
        }
    }

    // r5-verified cooperative stage of one 32-wide K chunk (hi+lo).
    auto stage = [&](const f16* __restrict__ Wh, const f16* __restrict__ Wl,
                     const int kst, const int kc) {
        #pragma unroll
        for (int i = 0; i < 2; i++) {
            const int c = 2 * w + i;
            const int ophys = c * 1024 + l * 16;
            const int olog  = ophys ^ (((ophys >> 7) & 3) << 4);
            const int row   = olog >> 6;
            const int slot  = (olog >> 4) & 3;
            glds16(Wh + (size_t)row * kst + kc * 32 + slot * 8, (char*)WH + c * 1024);
            glds16(Wl + (size_t)row * kst + kc * 32 + slot * 8, (char*)WL + c * 1024);
        }
    };

    // per-lane data gather for one frag (raw f32, 8 elems).
    auto gather = [&](int kc, int fi, float xv[8]) {
        if constexpr (MODE == 2) {
            #pragma unroll
            for (int j = 0; j < 8; j++) xv[j] = (lg == 0) ? feat[fi][j] : 0.f;
        } else {
            const float* src;
            if constexpr (MODE == 0) {
                if (kc < 4)      src = in0 + (size_t)sv[fi] * 128 + kc * 32 + lg * 8;
                else if (kc < 8) src = in0 + (size_t)rv[fi] * 128 + (kc - 4) * 32 + lg * 8;
                else             src = in1 + (size_t)egc[fi] * 128 + (kc - 8) * 32 + lg * 8;
            } else {
                if (kc < 4) src = in0 + (size_t)egc[fi] * 128 + kc * 32 + lg * 8;
                else        src = in1 + (size_t)egc[fi] * 128 + (kc - 4) * 32 + lg * 8;
            }
            const float4 x0 = *(const float4*)src;
            const float4 x1 = *(const float4*)(src + 4);
            xv[0] = x0.x; xv[1] = x0.y; xv[2] = x0.z; xv[3] = x0.w;
            xv[4] = x1.x; xv[5] = x1.y; xv[6] = x1.z; xv[7] = x1.w;
        }
    };

    auto cvt8 = [&](const float xv[8], f16x8& H, f16x8& L) {
        union { f16 h[8]; f16x8 v; } uh, ul;
        #pragma unroll
        for (int j = 0; j < 8; j++) {
            const f16 h = (f16)xv[j];
            uh.h[j] = h;
            ul.h[j] = (f16)((xv[j] - (float)h) * 2048.f);
        }
        H = uh.v; L = ul.v;
    };

    const f32x4 zero4 = {0.f, 0.f, 0.f, 0.f};
    f32x4 aH[2][8], aL[2][8];
    #pragma unroll
    for (int f = 0; f < 2; f++)
        #pragma unroll
        for (int mf = 0; mf < 8; mf++) { aH[f][mf] = zero4; aL[f][mf] = zero4; }

    float xn0[8], xn1[8];
    gather(0, 0, xn0);
    gather(0, 1, xn1);

    // ---------------- layer 1 (r5 2-barrier pattern) ----------------
    for (int kc = 0; kc < NCH1; ++kc) {
        __syncthreads();                  // prior readers of WH/WL done
        stage(W1h, W1l, K1S, kc);
        f16x8 XH[2], XL[2];
        cvt8(xn0, XH[0], XL[0]);
        cvt8(xn1, XH[1], XL[1]);
        __syncthreads();                  // weights staged (vmcnt drained)
        if (kc + 1 < NCH1) {              // prefetch next data chunk
            gather(kc + 1, 0, xn0);
            gather(kc + 1, 1, xn1);
        }
        #pragma unroll
        for (int mf = 0; mf < 8; mf++) {
            const int off = (mf * 16 + lr) * 64 + (swz << 4);
            const f16x8 wh = *(const f16x8*)((const char*)WH + off);
            const f16x8 wl = *(const f16x8*)((const char*)WL + off);
            #pragma unroll
            for (int f = 0; f < 2; f++) {
                aH[f][mf] = __builtin_amdgcn_mfma_f32_16x16x32_f16(XH[f], wh, aH[f][mf], 0, 0, 0);
                aL[f][mf] = __builtin_amdgcn_mfma_f32_16x16x32_f16(XL[f], wh, aL[f][mf], 0, 0, 0);
                aL[f][mf] = __builtin_amdgcn_mfma_f32_16x16x32_f16(XH[f], wl, aL[f][mf], 0, 0, 0);
            }
        }
    }

    // layer-1 epilogue: bias+relu -> f16 Y, wave-private rows (no barrier).
    #pragma unroll
    for (int f = 0; f < 2; f++) {
        #pragma unroll
        for (int mf = 0; mf < 8; mf++) {
            const float bb1 = b1[mf * 16 + lr];
            #pragma unroll
            for (int reg = 0; reg < 4; reg++) {
                float v = aH[f][mf][reg] + aL[f][mf][reg] * (1.f / 2048.f) + bb1;
                v = fmaxf(v, 0.f);
                union { f16 h; unsigned short u; } cc; cc.h = (f16)v;
                Yh[(w * 32 + f * 16 + lg * 4 + reg) * 136 + mf * 16 + lr] = cc.u;
            }
            aH[f][mf] = zero4; aL[f][mf] = zero4;
        }
    }

    // ---------------- layer 2 (f16 Y: 2 MFMAs per frag per mf) -----------
    for (int kc = 0; kc < 4; ++kc) {
        __syncthreads();
        stage(W2h, W2l, 128, kc);
        f16x8 XH[2];
        #pragma unroll
        for (int f = 0; f < 2; f++) {
            const unsigned short* yrow =
                Yh + (w * 32 + f * 16 + lr) * 136 + kc * 32 + lg * 8;
            union { uint4 q; f16x8 v; } cc;
            cc.q = *(const uint4*)(yrow);
            XH[f] = cc.v;
        }
        __syncthreads();
        #pragma unroll
        for (int mf = 0; mf < 8; mf++) {
            const int off = (mf * 16 + lr) * 64 + (swz << 4);
            const f16x8 wh = *(const f16x8*)((const char*)WH + off);
            const f16x8 wl = *(const f16x8*)((const char*)WL + off);
            #pragma unroll
            for (int f = 0; f < 2; f++) {
                aH[f][mf] = __builtin_amdgcn_mfma_f32_16x16x32_f16(XH[f], wh, aH[f][mf], 0, 0, 0);
                aL[f][mf] = __builtin_amdgcn_mfma_f32_16x16x32_f16(XH[f], wl, aL[f][mf], 0, 0, 0);
            }
        }
    }

    // layer-2 epilogue (verified pattern), per frag sequentially.
    float gg[8], b8[8];
    #pragma unroll
    for (int mf = 0; mf < 8; mf++) {
        gg[mf] = gam[mf * 16 + lr];
        b8[mf] = bet[mf * 16 + lr];
    }

    #pragma unroll
    for (int f = 0; f < 2; f++) {
        float vv[8][4];
        float s1[4] = {0, 0, 0, 0}, s2[4] = {0, 0, 0, 0};
        #pragma unroll
        for (int mf = 0; mf < 8; mf++) {
            const float bb2 = b2[mf * 16 + lr];
            #pragma unroll
            for (int reg = 0; reg < 4; reg++) {
                float v = aH[f][mf][reg] + aL[f][mf][reg] * (1.f / 2048.f) + bb2;
                v = fmaxf(v, 0.f);
                vv[mf][reg] = v;
                s1[reg] += v; s2[reg] += v * v;
            }
        }
        #pragma unroll
        for (int m = 1; m < 16; m <<= 1) {
            #pragma unroll
            for (int reg = 0; reg < 4; reg++) {
                s1[reg] += __shfl_xor(s1[reg], m);
                s2[reg] += __shfl_xor(s2[reg], m);
            }
        }
        #pragma unroll
        for (int reg = 0; reg < 4; reg++) {
            const float mu = s1[reg] * (1.f / 128.f);
            const float rs = rsqrtf(fmaxf(s2[reg] * (1.f / 128.f) - mu * mu, 0.f) + 1e-5f);
            const int idx = base + w * 32 + f * 16 + lg * 4 + reg;
            if (idx < nrows) {
                if constexpr (MODE == 0) {
                    const int rc = receivers[idx];
                    #pragma unroll
                    for (int mf = 0; mf < 8; mf++) {
                        const float o = gg[mf] * (vv[mf][reg] - mu) * rs + b8[mf];
                        atomicAdd(&aggr[(size_t)rc * 128 + mf * 16 + lr], o); // segsum
                        io[(size_t)idx * 128 + mf * 16 + lr] += o;            // el res
                    }
                } else if constexpr (MODE == 1) {
                    #pragma unroll
                    for (int mf = 0; mf < 8; mf++) {
                        const float o = gg[mf] * (vv[mf][reg] - mu) * rs + b8[mf];
                        io[(size_t)idx * 128 + mf * 16 + lr] += o;            // nl res
                    }
                } else {
                    #pragma unroll
                    for (int mf = 0; mf < 8; mf++) {
                        const float o = gg[mf] * (vv[mf][reg] - mu) * rs + b8[mf];
                        io[(size_t)idx * 128 + mf * 16 + lr] = o;             // el enc
                    }
                }
            }
        }
    }
}

// Decoder -> FLOAT32 output, layout [TW, N, TD].
__global__ __launch_bounds__(128) void decode_k(
    const float* __restrict__ nl,
    const float* __restrict__ W1, const float* __restrict__ b1,
    const float* __restrict__ W2, const float* __restrict__ b2,
    float* __restrict__ out)
{
    constexpr int NPB = 16;
    __shared__ __align__(16) float xs[NPB * LNUM];
    __shared__ float hh[NPB * 8];
    const int t = threadIdx.x;
    const int base = blockIdx.x * NPB;
    for (int r = 0; r < NPB; r++) xs[r * LNUM + t] = nl[(base + r) * LNUM + t];
    __syncthreads();
    {
        const int node = t >> 3, j = t & 7;
        float a = b1[j];
        for (int k = 0; k < LNUM; k++) a = fmaf(xs[node * LNUM + k], W1[k * 8 + j], a);
        hh[node * 8 + j] = a / (1.f + expf(-a));
    }
    __syncthreads();
    for (int idx = t; idx < NPB * 10; idx += 128) {
        const int node = idx / 10, c = idx % 10;
        float a = b2[c];
        #pragma unroll
        for (int j = 0; j < 8; j++) a = fmaf(hh[node * 8 + j], W2[j * 10 + c], a);
        const int tt = c >> 1, d = c & 1;
        out[(size_t)tt * (NNODES * 2) + (size_t)(base + node) * 2 + d] =
            a * (float)(tt + 1);
    }
}

__global__ __launch_bounds__(256) void zero_k(float* __restrict__ p, int n)
{
    const int i = blockIdx.x * 256 + threadIdx.x;
    if (i < n) p[i] = 0.f;
}

// ---------------------------------------------------------------------------
extern "C" void kernel_launch(void* const* d_in, const int* in_sizes, int n_in,
                              void* d_out, int out_size, void* d_ws, size_t ws_size,
                              hipStream_t stream) {
    const float* F[34];
    for (int i = 0; i < 34; i++) F[i] = (const float*)d_in[i];
    const int* senders   = (const int*)d_in[4];
    const int* receivers = (const int*)d_in[5];

    const size_t nN = (size_t)NNODES * LNUM;
    const size_t nE = (size_t)NEDGES * LNUM;
    float* nl   = (float*)d_ws;
    float* el   = nl + nN;
    float* aggr = el + nE;
    f16* wb = (f16*)(aggr + nN);
    f16 *eW1h = wb,          *eW1l = eW1h + PE1;
    f16 *eW2h = eW1l + PE1,  *eW2l = eW2h + PE2;
    f16 *nW1h = eW2l + PE2,  *nW1l = nW1h + PN1;
    f16 *nW2h = nW1l + PN1,  *nW2l = nW2h + PN2;
    f16 *qW1h = nW2l + PN2,  *qW1l = qW1h + PQ1;
    f16 *qW2h = qW1l + PQ1,  *qW2l = qW2h + PQ2;

    prep_w_all_k<<<(PTOT + 255) / 256, 256, 0, stream>>>(
        F[18], F[20], F[24], F[26], F[12], F[14], wb);

    encode_nodes_k<<<NNODES / 4, 128, 0, stream>>>(
        F[2], F[3], F[1], F[6], F[7], F[8], F[9], F[10], F[11], nl);

    const int egrid = (NEDGES + 127) / 128;   // 1172 blocks of 256 threads
    const int ngrid = (NNODES + 127) / 128;   // 235

    // edge encoder (MFMA, computed features)
    mfma_mlp_k<2, 1, 32><<<egrid, 256, 0, stream>>>(
        F[0], F[2], el, nullptr, senders, receivers,
        qW1h, qW1l, F[13], qW2h, qW2l, F[15], F[16], F[17], NEDGES);

    for (int s = 0; s < NSTEPS; s++) {
        zero_k<<<(NNODES * LNUM + 255) / 256, 256, 0, stream>>>(aggr, NNODES * LNUM);
        mfma_mlp_k<0, 12, 384><<<egrid, 256, 0, stream>>>(
            nl, el, el, aggr, senders, receivers,
            eW1h + (size_t)s * 384 * 128, eW1l + (size_t)s * 384 * 128, F[19] + s * LNUM,
            eW2h + (size_t)s * 128 * 128, eW2l + (size_t)s * 128 * 128, F[21] + s * LNUM,
            F[22] + s * LNUM, F[23] + s * LNUM, NEDGES);
        mfma_mlp_k<1, 8, 256><<<ngrid, 256, 0, stream>>>(
            nl, aggr, nl, nullptr, nullptr, nullptr,
            nW1h + (size_t)s * 256 * 128, nW1l + (size_t)s * 256 * 128, F[25] + s * LNUM,
            nW2h + (size_t)s * 128 * 128, nW2l + (size_t)s * 128 * 128, F[27] + s * LNUM,
            F[28] + s * LNUM, F[29] + s * LNUM, NNODES);
    }

    decode_k<<<NNODES / 16, 128, 0, stream>>>(
        nl, F[30], F[31], F[32], F[33], (float*)d_out);
}

// Round 9
// 876.533 us; speedup vs baseline: 1.7793x; 1.7706x over previous
//
#include <hip/hip_runtime.h>
#include <hip/hip_bf16.h>

#define LNUM 128
#define NNODES 30000
#define NEDGES 150000
#define NSTEPS 5

// NOTE (r17 discovery): d_out is FLOAT32 (reference is pure jnp.float32).
// r8 post-mortem: time tracks total wave count (ILP null); f16-Y cost absmax
// NOTHING (0.0078125 bit-identical) -> precision budget has headroom.
// r9: r5 structure (64 edges/block, 256thr, 1 frag, 2-barrier K-step) with
//  - f16-ONLY weights (drop weight-lo: halves stage+LDS-reads, -33% MFMAs;
//    est absmax 0.015-0.03 vs thr 0.044) ; data stays exact via UNSCALED lo
//    XL=(f16)(x-hi): acc = XH*wh + XL*wh, no /2048 recombine, single chain.
//  - f16-only Y (r8-verified) in 16KB XOR-swizzled LDS (byte ^= (row&7)<<4)
//  - LDS 24.6KB (6 blk/CU cap) + __launch_bounds__(256,5) (VGPR<=102)
//    -> theoretical 20 waves/CU (62.5%) vs r5's 37.5%.

typedef _Float16 f16;
typedef __attribute__((ext_vector_type(8))) _Float16 f16x8;
typedef __attribute__((ext_vector_type(4))) float f32x4;

__device__ __forceinline__ void glds16(const void* g, void* l) {
    __builtin_amdgcn_global_load_lds(
        (const __attribute__((address_space(1))) void*)g,
        (__attribute__((address_space(3))) void*)l, 16, 0, 0);
}

// ---------------------------------------------------------------------------
// Legacy VALU MLP core: still used by the (small) encode_nodes kernel.
// ---------------------------------------------------------------------------
template<int ROWS, int K, int KP>
__device__ __forceinline__ void mlp_apply(
    const float* __restrict__ xs, float* __restrict__ hv,
    float* __restrict__ mu_s, float* __restrict__ rs_s,
    const float* __restrict__ W1, const float* __restrict__ b1,
    const float* __restrict__ W2, const float* __restrict__ b2,
    const float* __restrict__ g,  const float* __restrict__ be,
    float out[ROWS])
{
    const int t = threadIdx.x;
    float acc[ROWS];
    {
        const float bb = b1[t];
        #pragma unroll
        for (int r = 0; r < ROWS; r++) acc[r] = bb;
    }
    int k = 0;
    for (; k + 4 <= K; k += 4) {
        const float w0 = W1[(k + 0) * LNUM + t];
        const float w1 = W1[(k + 1) * LNUM + t];
        const float w2 = W1[(k + 2) * LNUM + t];
        const float w3 = W1[(k + 3) * LNUM + t];
        #pragma unroll
        for (int r = 0; r < ROWS; r++) {
            const float4 x = *(const float4*)(xs + r * KP + k);
            acc[r] = fmaf(x.x, w0, acc[r]);
            acc[r] = fmaf(x.y, w1, acc[r]);
            acc[r] = fmaf(x.z, w2, acc[r]);
            acc[r] = fmaf(x.w, w3, acc[r]);
        }
    }
    for (; k < K; ++k) {
        const float w = W1[k * LNUM + t];
        #pragma unroll
        for (int r = 0; r < ROWS; r++) acc[r] = fmaf(xs[r * KP + k], w, acc[r]);
    }
    #pragma unroll
    for (int r = 0; r < ROWS; r++) hv[r * LNUM + t] = fmaxf(acc[r], 0.f);
    __syncthreads();
    {
        const float bb = b2[t];
        #pragma unroll
        for (int r = 0; r < ROWS; r++) acc[r] = bb;
    }
    for (int k2 = 0; k2 < LNUM; k2 += 4) {
        const float w0 = W2[(k2 + 0) * LNUM + t];
        const float w1 = W2[(k2 + 1) * LNUM + t];
        const float w2 = W2[(k2 + 2) * LNUM + t];
        const float w3 = W2[(k2 + 3) * LNUM + t];
        #pragma unroll
        for (int r = 0; r < ROWS; r++) {
            const float4 x = *(const float4*)(hv + r * LNUM + k2);
            acc[r] = fmaf(x.x, w0, acc[r]);
            acc[r] = fmaf(x.y, w1, acc[r]);
            acc[r] = fmaf(x.z, w2, acc[r]);
            acc[r] = fmaf(x.w, w3, acc[r]);
        }
    }
    __syncthreads();
    #pragma unroll
    for (int r = 0; r < ROWS; r++) hv[r * LNUM + t] = fmaxf(acc[r], 0.f);
    __syncthreads();
    if (t < ROWS) {
        float s = 0.f, s2 = 0.f;
        for (int kk = 0; kk < LNUM; kk++) {
            const float v = hv[t * LNUM + kk];
            s += v; s2 += v * v;
        }
        const float m = s * (1.0f / LNUM);
        mu_s[t] = m;
        rs_s[t] = rsqrtf(fmaxf(s2 * (1.0f / LNUM) - m * m, 0.f) + 1e-5f);
    }
    __syncthreads();
    const float gg = g[t], bbe = be[t];
    #pragma unroll
    for (int r = 0; r < ROWS; r++)
        out[r] = fmaf(gg * (hv[r * LNUM + t] - mu_s[r]), rs_s[r], bbe);
}

__global__ __launch_bounds__(128) void encode_nodes_k(
    const float* __restrict__ u, const float* __restrict__ load_,
    const float* __restrict__ ntype,
    const float* __restrict__ W1, const float* __restrict__ b1,
    const float* __restrict__ W2, const float* __restrict__ b2,
    const float* __restrict__ g,  const float* __restrict__ be,
    float* __restrict__ nl)
{
    constexpr int ROWS = 4, K = 12, KP = 12;
    __shared__ __align__(16) float xs[ROWS * KP];
    __shared__ __align__(16) float hv[ROWS * LNUM];
    __shared__ float mu_s[ROWS], rs_s[ROWS];
    const int t = threadIdx.x;
    const int base = blockIdx.x * ROWS;
    if (t < ROWS * K) {
        const int r = t / K, k = t % K;
        const int n = base + r;
        float v;
        if (k < 2)      v = u[n * 2 + k];
        else if (k < 3) v = load_[n];
        else            v = ntype[n * 9 + (k - 3)];
        xs[r * KP + k] = v;
    }
    __syncthreads();
    float out[ROWS];
    mlp_apply<ROWS, K, KP>(xs, hv, mu_s, rs_s, W1, b1, W2, b2, g, be, out);
    #pragma unroll
    for (int r = 0; r < ROWS; r++) nl[(base + r) * LNUM + t] = out[r];
}

// ---------------------------------------------------------------------------
// Weight prep: f32 [S][K][128] -> f16 hi tables transposed to [S][128][K].
// (lo tables no longer used by the MFMA kernels; only hi is written.)
// ---------------------------------------------------------------------------
#define PE1 245760   // 5*384*128 (edge W1)
#define PE2 81920    // 5*128*128 (edge W2)
#define PN1 163840   // 5*256*128 (node W1)
#define PN2 81920    // 5*128*128 (node W2)
#define PQ1 4096     // 128*32    (enc-edge W1, k-padded)
#define PQ2 16384    // 128*128   (enc-edge W2)
#define PTOT (PE1+PE2+PN1+PN2+PQ1+PQ2)

__global__ __launch_bounds__(256) void prep_w_all_k(
    const float* __restrict__ eW1, const float* __restrict__ eW2,
    const float* __restrict__ nW1, const float* __restrict__ nW2,
    const float* __restrict__ qW1, const float* __restrict__ qW2,
    f16* __restrict__ out)
{
    int j = blockIdx.x * 256 + threadIdx.x;
    if (j >= PTOT) return;
    const float* W; int K, kreal; f16* hi; f16* p = out;
    if (j < PE1) { W = eW1; K = 384; kreal = 384; hi = p; }
    else { p += PE1; j -= PE1;
    if (j < PE2) { W = eW2; K = 128; kreal = 128; hi = p; }
    else { p += PE2; j -= PE2;
    if (j < PN1) { W = nW1; K = 256; kreal = 256; hi = p; }
    else { p += PN1; j -= PN1;
    if (j < PN2) { W = nW2; K = 128; kreal = 128; hi = p; }
    else { p += PN2; j -= PN2;
    if (j < PQ1) { W = qW1; K = 32;  kreal = 5;   hi = p; }
    else { p += PQ1; j -= PQ1;
         { W = qW2; K = 128; kreal = 128; hi = p; } } } } } }
    const int k = j % K;
    const int rem = j / K;
    const int n = rem & 127;
    const int s = rem >> 7;
    const float v = (k < kreal) ? W[((size_t)s * kreal + k) * 128 + n] : 0.f;
    hi[j] = (f16)v;
}

// ---------------------------------------------------------------------------
// MFMA MLP, f16 weights, r5 structure. 256 thr = 4 waves, 64 rows/block.
// Weights: ONE 32-wide K chunk (hi only, 8KB) staged per iter (r5-verified
// glds16 + XOR swizzle, 2 barriers/chunk). Data exact via unscaled lo:
// acc = XH*wh + XL*wh with XL = (f16)(x - hi)  [no recombination scaling].
// Layer1->2 via f16-only Y (r8-verified) in 16KB XOR-swizzled LDS
// (byte ^= (row&7)<<4 within each row; write scalar u16, read 16B vector).
// Layer 2 input is exactly f16 -> single MFMA per mf per chunk.
// D layout (verified): edge = w*16+lg*4+reg, feature = mf*16+lr
// -> epilogue writes/atomics are 16-consecutive-col (full 64B lines).
// MODE: 0 = edge block, 1 = node block, 2 = edge encoder.
// ---------------------------------------------------------------------------
template<int MODE, int NCH1, int K1S>
__global__ __launch_bounds__(256, 5) void mfma_mlp_k(
    const float* __restrict__ in0, const float* __restrict__ in1,
    float* __restrict__ io, float* __restrict__ aggr,
    const int* __restrict__ senders, const int* __restrict__ receivers,
    const f16* __restrict__ W1h, const float* __restrict__ b1,
    const f16* __restrict__ W2h, const float* __restrict__ b2,
    const float* __restrict__ gam, const float* __restrict__ bet,
    int nrows)
{
    __shared__ __align__(16) f16 WH[4096];                 // [128][32] swz, 8KB
    __shared__ __align__(16) unsigned short Yh[64 * 128];  // f16, swizzled, 16KB

    const int t  = threadIdx.x;
    const int w  = t >> 6;
    const int l  = t & 63;
    const int lr = l & 15;
    const int lg = l >> 4;
    const int swz = lg ^ ((lr >> 1) & 3);
    const int base = blockIdx.x * 64;

    const int eg  = base + w * 16 + lr;    // this lane's gather row (A-row)
    const int egc = min(eg, nrows - 1);

    int sv = 0, rv = 0;
    if constexpr (MODE != 1) { sv = senders[egc]; rv = receivers[egc]; }

    float feat[8];
    if constexpr (MODE == 2) {
        const float ax = in0[sv * 2], ay = in0[sv * 2 + 1];
        const float bx = in0[rv * 2], by = in0[rv * 2 + 1];
        const float rx = ax - bx, ry = ay - by;
        feat[0] = rx; feat[1] = ry; feat[2] = sqrtf(rx * rx + ry * ry);
        feat[3] = in1[sv * 2] - in1[rv * 2];
        feat[4] = in1[sv * 2 + 1] - in1[rv * 2 + 1];
        feat[5] = 0.f; feat[6] = 0.f; feat[7] = 0.f;
    }

    // r5-verified cooperative stage of one 32-wide K chunk (hi only).
    auto stage = [&](const f16* __restrict__ Wh, const int kst, const int kc) {
        #pragma unroll
        for (int i = 0; i < 2; i++) {
            const int c = 2 * w + i;
            const int ophys = c * 1024 + l * 16;
            const int olog  = ophys ^ (((ophys >> 7) & 3) << 4);
            const int row   = olog >> 6;
            const int slot  = (olog >> 4) & 3;
            glds16(Wh + (size_t)row * kst + kc * 32 + slot * 8, (char*)WH + c * 1024);
        }
    };

    // r4/r5-verified per-lane data gather (raw f32, 8 elems).
    auto gather = [&](int kc, float xv[8]) {
        if constexpr (MODE == 2) {
            #pragma unroll
            for (int j = 0; j < 8; j++) xv[j] = (lg == 0) ? feat[j] : 0.f;
        } else {
            const float* src;
            if constexpr (MODE == 0) {
                if (kc < 4)      src = in0 + (size_t)sv  * 128 + kc * 32 + lg * 8;
                else if (kc < 8) src = in0 + (size_t)rv  * 128 + (kc - 4) * 32 + lg * 8;
                else             src = in1 + (size_t)egc * 128 + (kc - 8) * 32 + lg * 8;
            } else {
                if (kc < 4) src = in0 + (size_t)egc * 128 + kc * 32 + lg * 8;
                else        src = in1 + (size_t)egc * 128 + (kc - 4) * 32 + lg * 8;
            }
            const float4 x0 = *(const float4*)src;
            const float4 x1 = *(const float4*)(src + 4);
            xv[0] = x0.x; xv[1] = x0.y; xv[2] = x0.z; xv[3] = x0.w;
            xv[4] = x1.x; xv[5] = x1.y; xv[6] = x1.z; xv[7] = x1.w;
        }
    };

    const f32x4 zero4 = {0.f, 0.f, 0.f, 0.f};
    f32x4 acc[8];
    #pragma unroll
    for (int mf = 0; mf < 8; mf++) acc[mf] = zero4;

    float xnext[8];
    gather(0, xnext);

    // ---------------- layer 1 (r5 2-barrier pattern) ----------------
    for (int kc = 0; kc < NCH1; ++kc) {
        __syncthreads();                  // prior readers of WH done
        stage(W1h, K1S, kc);
        union { f16 h[8]; f16x8 v; } XH, XL;
        #pragma unroll
        for (int j = 0; j < 8; j++) {
            const f16 h = (f16)xnext[j];
            XH.h[j] = h;
            XL.h[j] = (f16)(xnext[j] - (float)h);   // UNSCALED lo: exact sum
        }
        __syncthreads();                  // weights staged (vmcnt drained)
        if (kc + 1 < NCH1) gather(kc + 1, xnext);   // prefetch next chunk
        #pragma unroll
        for (int mf = 0; mf < 8; mf++) {
            const int off = (mf * 16 + lr) * 64 + (swz << 4);
            const f16x8 wh = *(const f16x8*)((const char*)WH + off);
            acc[mf] = __builtin_amdgcn_mfma_f32_16x16x32_f16(XH.v, wh, acc[mf], 0, 0, 0);
            acc[mf] = __builtin_amdgcn_mfma_f32_16x16x32_f16(XL.v, wh, acc[mf], 0, 0, 0);
        }
    }

    // layer-1 epilogue: lane holds h1[edge = lg*4+reg][feat = mf*16+lr].
    // bias+relu -> f16 Y at XOR-swizzled addr (wave-private rows, no barrier).
    #pragma unroll
    for (int mf = 0; mf < 8; mf++) {
        const float bb1 = b1[mf * 16 + lr];
        #pragma unroll
        for (int reg = 0; reg < 4; reg++) {
            float v = acc[mf][reg] + bb1;
            v = fmaxf(v, 0.f);
            union { f16 h; unsigned short u; } cc; cc.h = (f16)v;
            const int row = w * 16 + lg * 4 + reg;
            const int cb  = (mf * 16 + lr) * 2;
            *(unsigned short*)((char*)Yh + row * 256 +
                               (cb ^ (((lg * 4 + reg) & 7) << 4))) = cc.u;
        }
        acc[mf] = zero4;
    }

    // ---------------- layer 2 (f16 Y exact -> 1 MFMA per mf) ----------
    for (int kc = 0; kc < 4; ++kc) {
        __syncthreads();                  // prior readers of WH done
        stage(W2h, 128, kc);
        union { uint4 q; f16x8 v; } YH;
        {
            const int row = w * 16 + lr;
            const int cb  = (kc * 32 + lg * 8) * 2;
            YH.q = *(const uint4*)((const char*)Yh + row * 256 +
                                   (cb ^ ((lr & 7) << 4)));
        }
        __syncthreads();                  // weights staged
        #pragma unroll
        for (int mf = 0; mf < 8; mf++) {
            const int off = (mf * 16 + lr) * 64 + (swz << 4);
            const f16x8 wh = *(const f16x8*)((const char*)WH + off);
            acc[mf] = __builtin_amdgcn_mfma_f32_16x16x32_f16(YH.v, wh, acc[mf], 0, 0, 0);
        }
    }

    // layer-2 epilogue (r5-verified): bias+relu+LN+apply+store.
    float vv[8][4];
    float s1[4] = {0, 0, 0, 0}, s2[4] = {0, 0, 0, 0};
    #pragma unroll
    for (int mf = 0; mf < 8; mf++) {
        const float bb2 = b2[mf * 16 + lr];
        #pragma unroll
        for (int reg = 0; reg < 4; reg++) {
            float v = acc[mf][reg] + bb2;
            v = fmaxf(v, 0.f);
            vv[mf][reg] = v;
            s1[reg] += v; s2[reg] += v * v;
        }
    }
    #pragma unroll
    for (int m = 1; m < 16; m <<= 1) {
        #pragma unroll
        for (int reg = 0; reg < 4; reg++) {
            s1[reg] += __shfl_xor(s1[reg], m);
            s2[reg] += __shfl_xor(s2[reg], m);
        }
    }
    float gg[8], b8[8];
    #pragma unroll
    for (int mf = 0; mf < 8; mf++) {
        gg[mf] = gam[mf * 16 + lr];
        b8[mf] = bet[mf * 16 + lr];
    }

    #pragma unroll
    for (int reg = 0; reg < 4; reg++) {
        const float mu = s1[reg] * (1.f / 128.f);
        const float rs = rsqrtf(fmaxf(s2[reg] * (1.f / 128.f) - mu * mu, 0.f) + 1e-5f);
        const int row = w * 16 + lg * 4 + reg;
        const int idx = base + row;
        if (idx < nrows) {
            if constexpr (MODE == 0) {
                const int rc = receivers[idx];
                #pragma unroll
                for (int mf = 0; mf < 8; mf++) {
                    const float o = gg[mf] * (vv[mf][reg] - mu) * rs + b8[mf];
                    atomicAdd(&aggr[(size_t)rc * 128 + mf * 16 + lr], o); // segsum
                    io[(size_t)idx * 128 + mf * 16 + lr] += o;            // el res
                }
            } else if constexpr (MODE == 1) {
                #pragma unroll
                for (int mf = 0; mf < 8; mf++) {
                    const float o = gg[mf] * (vv[mf][reg] - mu) * rs + b8[mf];
                    io[(size_t)idx * 128 + mf * 16 + lr] += o;            // nl res
                }
            } else {
                #pragma unroll
                for (int mf = 0; mf < 8; mf++) {
                    const float o = gg[mf] * (vv[mf][reg] - mu) * rs + b8[mf];
                    io[(size_t)idx * 128 + mf * 16 + lr] = o;             // el enc
                }
            }
        }
    }
}

// Decoder -> FLOAT32 output, layout [TW, N, TD].
__global__ __launch_bounds__(128) void decode_k(
    const float* __restrict__ nl,
    const float* __restrict__ W1, const float* __restrict__ b1,
    const float* __restrict__ W2, const float* __restrict__ b2,
    float* __restrict__ out)
{
    constexpr int NPB = 16;
    __shared__ __align__(16) float xs[NPB * LNUM];
    __shared__ float hh[NPB * 8];
    const int t = threadIdx.x;
    const int base = blockIdx.x * NPB;
    for (int r = 0; r < NPB; r++) xs[r * LNUM + t] = nl[(base + r) * LNUM + t];
    __syncthreads();
    {
        const int node = t >> 3, j = t & 7;
        float a = b1[j];
        for (int k = 0; k < LNUM; k++) a = fmaf(xs[node * LNUM + k], W1[k * 8 + j], a);
        hh[node * 8 + j] = a / (1.f + expf(-a));
    }
    __syncthreads();
    for (int idx = t; idx < NPB * 10; idx += 128) {
        const int node = idx / 10, c = idx % 10;
        float a = b2[c];
        #pragma unroll
        for (int j = 0; j < 8; j++) a = fmaf(hh[node * 8 + j], W2[j * 10 + c], a);
        const int tt = c >> 1, d = c & 1;
        out[(size_t)tt * (NNODES * 2) + (size_t)(base + node) * 2 + d] =
            a * (float)(tt + 1);
    }
}

__global__ __launch_bounds__(256) void zero_k(float* __restrict__ p, int n)
{
    const int i = blockIdx.x * 256 + threadIdx.x;
    if (i < n) p[i] = 0.f;
}

// ---------------------------------------------------------------------------
extern "C" void kernel_launch(void* const* d_in, const int* in_sizes, int n_in,
                              void* d_out, int out_size, void* d_ws, size_t ws_size,
                              hipStream_t stream) {
    const float* F[34];
    for (int i = 0; i < 34; i++) F[i] = (const float*)d_in[i];
    const int* senders   = (const int*)d_in[4];
    const int* receivers = (const int*)d_in[5];

    const size_t nN = (size_t)NNODES * LNUM;
    const size_t nE = (size_t)NEDGES * LNUM;
    float* nl   = (float*)d_ws;
    float* el   = nl + nN;
    float* aggr = el + nE;
    f16* wb = (f16*)(aggr + nN);
    f16 *eW1h = wb;
    f16 *eW2h = eW1h + PE1;
    f16 *nW1h = eW2h + PE2;
    f16 *nW2h = nW1h + PN1;
    f16 *qW1h = nW2h + PN2;
    f16 *qW2h = qW1h + PQ1;

    prep_w_all_k<<<(PTOT + 255) / 256, 256, 0, stream>>>(
        F[18], F[20], F[24], F[26], F[12], F[14], wb);

    encode_nodes_k<<<NNODES / 4, 128, 0, stream>>>(
        F[2], F[3], F[1], F[6], F[7], F[8], F[9], F[10], F[11], nl);

    const int egrid = (NEDGES + 63) / 64;   // 2344 blocks of 256 threads
    const int ngrid = (NNODES + 63) / 64;   // 469

    // edge encoder (MFMA, computed features)
    mfma_mlp_k<2, 1, 32><<<egrid, 256, 0, stream>>>(
        F[0], F[2], el, nullptr, senders, receivers,
        qW1h, F[13], qW2h, F[15], F[16], F[17], NEDGES);

    for (int s = 0; s < NSTEPS; s++) {
        zero_k<<<(NNODES * LNUM + 255) / 256, 256, 0, stream>>>(aggr, NNODES * LNUM);
        mfma_mlp_k<0, 12, 384><<<egrid, 256, 0, stream>>>(
            nl, el, el, aggr, senders, receivers,
            eW1h + (size_t)s * 384 * 128, F[19] + s * LNUM,
            eW2h + (size_t)s * 128 * 128, F[21] + s * LNUM,
            F[22] + s * LNUM, F[23] + s * LNUM, NEDGES);
        mfma_mlp_k<1, 8, 256><<<ngrid, 256, 0, stream>>>(
            nl, aggr, nl, nullptr, nullptr, nullptr,
            nW1h + (size_t)s * 256 * 128, F[25] + s * LNUM,
            nW2h + (size_t)s * 128 * 128, F[27] + s * LNUM,
            F[28] + s * LNUM, F[29] + s * LNUM, NNODES);
    }

    decode_k<<<NNODES / 16, 128, 0, stream>>>(
        nl, F[30], F[31], F[32], F[33], (float*)d_out);
}

// Round 10
// 793.693 us; speedup vs baseline: 1.9650x; 1.1044x over previous
//
#include <hip/hip_runtime.h>
#include <hip/hip_bf16.h>

#define LNUM 128
#define NNODES 30000
#define NEDGES 150000
#define NSTEPS 5

// NOTE (r17 discovery): d_out is FLOAT32 (reference is pure jnp.float32).
// r9 post-mortem: 876us, edge 117.5us now traffic-bound on f32 latents
// (WRITE 152MB = el 76.8 + atomics 76.8; FETCH 125MB). f16-weights cost
// absmax NOTHING -> budget headroom. r10: nl/el stored as f16 (aggr stays
// f32): halves el traffic, nl (7.7MB) becomes L2-resident, and f16 data is
// EXACT -> data-lo MFMA + split-convert VALU vanish for f16 chunks.
// Node kernel keeps unscaled-lo split only for f32 aggr chunks.

typedef _Float16 f16;
typedef __attribute__((ext_vector_type(8))) _Float16 f16x8;
typedef __attribute__((ext_vector_type(4))) float f32x4;

__device__ __forceinline__ void glds16(const void* g, void* l) {
    __builtin_amdgcn_global_load_lds(
        (const __attribute__((address_space(1))) void*)g,
        (__attribute__((address_space(3))) void*)l, 16, 0, 0);
}

// ---------------------------------------------------------------------------
// Legacy VALU MLP core: still used by the (small) encode_nodes kernel.
// ---------------------------------------------------------------------------
template<int ROWS, int K, int KP>
__device__ __forceinline__ void mlp_apply(
    const float* __restrict__ xs, float* __restrict__ hv,
    float* __restrict__ mu_s, float* __restrict__ rs_s,
    const float* __restrict__ W1, const float* __restrict__ b1,
    const float* __restrict__ W2, const float* __restrict__ b2,
    const float* __restrict__ g,  const float* __restrict__ be,
    float out[ROWS])
{
    const int t = threadIdx.x;
    float acc[ROWS];
    {
        const float bb = b1[t];
        #pragma unroll
        for (int r = 0; r < ROWS; r++) acc[r] = bb;
    }
    int k = 0;
    for (; k + 4 <= K; k += 4) {
        const float w0 = W1[(k + 0) * LNUM + t];
        const float w1 = W1[(k + 1) * LNUM + t];
        const float w2 = W1[(k + 2) * LNUM + t];
        const float w3 = W1[(k + 3) * LNUM + t];
        #pragma unroll
        for (int r = 0; r < ROWS; r++) {
            const float4 x = *(const float4*)(xs + r * KP + k);
            acc[r] = fmaf(x.x, w0, acc[r]);
            acc[r] = fmaf(x.y, w1, acc[r]);
            acc[r] = fmaf(x.z, w2, acc[r]);
            acc[r] = fmaf(x.w, w3, acc[r]);
        }
    }
    for (; k < K; ++k) {
        const float w = W1[k * LNUM + t];
        #pragma unroll
        for (int r = 0; r < ROWS; r++) acc[r] = fmaf(xs[r * KP + k], w, acc[r]);
    }
    #pragma unroll
    for (int r = 0; r < ROWS; r++) hv[r * LNUM + t] = fmaxf(acc[r], 0.f);
    __syncthreads();
    {
        const float bb = b2[t];
        #pragma unroll
        for (int r = 0; r < ROWS; r++) acc[r] = bb;
    }
    for (int k2 = 0; k2 < LNUM; k2 += 4) {
        const float w0 = W2[(k2 + 0) * LNUM + t];
        const float w1 = W2[(k2 + 1) * LNUM + t];
        const float w2 = W2[(k2 + 2) * LNUM + t];
        const float w3 = W2[(k2 + 3) * LNUM + t];
        #pragma unroll
        for (int r = 0; r < ROWS; r++) {
            const float4 x = *(const float4*)(hv + r * LNUM + k2);
            acc[r] = fmaf(x.x, w0, acc[r]);
            acc[r] = fmaf(x.y, w1, acc[r]);
            acc[r] = fmaf(x.z, w2, acc[r]);
            acc[r] = fmaf(x.w, w3, acc[r]);
        }
    }
    __syncthreads();
    #pragma unroll
    for (int r = 0; r < ROWS; r++) hv[r * LNUM + t] = fmaxf(acc[r], 0.f);
    __syncthreads();
    if (t < ROWS) {
        float s = 0.f, s2 = 0.f;
        for (int kk = 0; kk < LNUM; kk++) {
            const float v = hv[t * LNUM + kk];
            s += v; s2 += v * v;
        }
        const float m = s * (1.0f / LNUM);
        mu_s[t] = m;
        rs_s[t] = rsqrtf(fmaxf(s2 * (1.0f / LNUM) - m * m, 0.f) + 1e-5f);
    }
    __syncthreads();
    const float gg = g[t], bbe = be[t];
    #pragma unroll
    for (int r = 0; r < ROWS; r++)
        out[r] = fmaf(gg * (hv[r * LNUM + t] - mu_s[r]), rs_s[r], bbe);
}

__global__ __launch_bounds__(128) void encode_nodes_k(
    const float* __restrict__ u, const float* __restrict__ load_,
    const float* __restrict__ ntype,
    const float* __restrict__ W1, const float* __restrict__ b1,
    const float* __restrict__ W2, const float* __restrict__ b2,
    const float* __restrict__ g,  const float* __restrict__ be,
    f16* __restrict__ nl)
{
    constexpr int ROWS = 4, K = 12, KP = 12;
    __shared__ __align__(16) float xs[ROWS * KP];
    __shared__ __align__(16) float hv[ROWS * LNUM];
    __shared__ float mu_s[ROWS], rs_s[ROWS];
    const int t = threadIdx.x;
    const int base = blockIdx.x * ROWS;
    if (t < ROWS * K) {
        const int r = t / K, k = t % K;
        const int n = base + r;
        float v;
        if (k < 2)      v = u[n * 2 + k];
        else if (k < 3) v = load_[n];
        else            v = ntype[n * 9 + (k - 3)];
        xs[r * KP + k] = v;
    }
    __syncthreads();
    float out[ROWS];
    mlp_apply<ROWS, K, KP>(xs, hv, mu_s, rs_s, W1, b1, W2, b2, g, be, out);
    #pragma unroll
    for (int r = 0; r < ROWS; r++) nl[(base + r) * LNUM + t] = (f16)out[r];
}

// ---------------------------------------------------------------------------
// Weight prep: f32 [S][K][128] -> f16 hi tables transposed to [S][128][K].
// ---------------------------------------------------------------------------
#define PE1 245760   // 5*384*128 (edge W1)
#define PE2 81920    // 5*128*128 (edge W2)
#define PN1 163840   // 5*256*128 (node W1)
#define PN2 81920    // 5*128*128 (node W2)
#define PQ1 4096     // 128*32    (enc-edge W1, k-padded)
#define PQ2 16384    // 128*128   (enc-edge W2)
#define PTOT (PE1+PE2+PN1+PN2+PQ1+PQ2)

__global__ __launch_bounds__(256) void prep_w_all_k(
    const float* __restrict__ eW1, const float* __restrict__ eW2,
    const float* __restrict__ nW1, const float* __restrict__ nW2,
    const float* __restrict__ qW1, const float* __restrict__ qW2,
    f16* __restrict__ out)
{
    int j = blockIdx.x * 256 + threadIdx.x;
    if (j >= PTOT) return;
    const float* W; int K, kreal; f16* hi; f16* p = out;
    if (j < PE1) { W = eW1; K = 384; kreal = 384; hi = p; }
    else { p += PE1; j -= PE1;
    if (j < PE2) { W = eW2; K = 128; kreal = 128; hi = p; }
    else { p += PE2; j -= PE2;
    if (j < PN1) { W = nW1; K = 256; kreal = 256; hi = p; }
    else { p += PN1; j -= PN1;
    if (j < PN2) { W = nW2; K = 128; kreal = 128; hi = p; }
    else { p += PN2; j -= PN2;
    if (j < PQ1) { W = qW1; K = 32;  kreal = 5;   hi = p; }
    else { p += PQ1; j -= PQ1;
         { W = qW2; K = 128; kreal = 128; hi = p; } } } } } }
    const int k = j % K;
    const int rem = j / K;
    const int n = rem & 127;
    const int s = rem >> 7;
    const float v = (k < kreal) ? W[((size_t)s * kreal + k) * 128 + n] : 0.f;
    hi[j] = (f16)v;
}

// ---------------------------------------------------------------------------
// MFMA MLP, f16 weights + f16 latents. 256 thr = 4 waves, 64 rows/block.
// Weights: ONE 32-wide K chunk (8KB) staged per iter (r5-verified glds16 +
// XOR swizzle, 2 barriers/chunk). f16 data chunks: EXACT, single MFMA/mf
// (no lo). f32 chunks (MODE1 aggr, MODE2 feat): unscaled-lo split, 2 MFMA/mf.
// Layer1->2 via f16-only Y in 16KB XOR-swizzled LDS (r9-verified).
// D layout (verified): edge = w*16+lg*4+reg, feature = mf*16+lr.
// MODE: 0 = edge block (Lat=nl16, io=el16 RMW, aggr atomics)
//       1 = node block (io=nl16 RMW, Fa=aggr f32)
//       2 = edge encoder (Fa=mesh_pos, Fb=u, io=el16 store)
// ---------------------------------------------------------------------------
template<int MODE, int NCH1, int K1S>
__global__ __launch_bounds__(256, 6) void mfma_mlp_k(
    const f16* __restrict__ Lat, const float* __restrict__ Fa,
    const float* __restrict__ Fb,
    f16* __restrict__ io, float* __restrict__ aggr,
    const int* __restrict__ senders, const int* __restrict__ receivers,
    const f16* __restrict__ W1h, const float* __restrict__ b1,
    const f16* __restrict__ W2h, const float* __restrict__ b2,
    const float* __restrict__ gam, const float* __restrict__ bet,
    int nrows)
{
    __shared__ __align__(16) f16 WH[4096];                 // [128][32] swz, 8KB
    __shared__ __align__(16) unsigned short Yh[64 * 128];  // f16, swizzled, 16KB

    const int t  = threadIdx.x;
    const int w  = t >> 6;
    const int l  = t & 63;
    const int lr = l & 15;
    const int lg = l >> 4;
    const int swz = lg ^ ((lr >> 1) & 3);
    const int base = blockIdx.x * 64;

    const int eg  = base + w * 16 + lr;    // this lane's gather row (A-row)
    const int egc = min(eg, nrows - 1);

    int sv = 0, rv = 0;
    if constexpr (MODE != 1) { sv = senders[egc]; rv = receivers[egc]; }

    float feat[8];
    if constexpr (MODE == 2) {
        const float ax = Fa[sv * 2], ay = Fa[sv * 2 + 1];
        const float bx = Fa[rv * 2], by = Fa[rv * 2 + 1];
        const float rx = ax - bx, ry = ay - by;
        feat[0] = rx; feat[1] = ry; feat[2] = sqrtf(rx * rx + ry * ry);
        feat[3] = Fb[sv * 2] - Fb[rv * 2];
        feat[4] = Fb[sv * 2 + 1] - Fb[rv * 2 + 1];
        feat[5] = 0.f; feat[6] = 0.f; feat[7] = 0.f;
    }

    // r5-verified cooperative stage of one 32-wide K chunk.
    auto stage = [&](const f16* __restrict__ Wh, const int kst, const int kc) {
        #pragma unroll
        for (int i = 0; i < 2; i++) {
            const int c = 2 * w + i;
            const int ophys = c * 1024 + l * 16;
            const int olog  = ophys ^ (((ophys >> 7) & 3) << 4);
            const int row   = olog >> 6;
            const int slot  = (olog >> 4) & 3;
            glds16(Wh + (size_t)row * kst + kc * 32 + slot * 8, (char*)WH + c * 1024);
        }
    };

    // prefetch regs: qn for f16 chunks, xn for f32 chunks
    uint4 qn;
    float xn[8];
    auto prefetch = [&](int kc) {
        if constexpr (MODE == 0) {
            const f16* src;
            if (kc < 4)      src = Lat + (size_t)sv  * 128 + kc * 32 + lg * 8;
            else if (kc < 8) src = Lat + (size_t)rv  * 128 + (kc - 4) * 32 + lg * 8;
            else             src = io  + (size_t)egc * 128 + (kc - 8) * 32 + lg * 8;
            qn = *(const uint4*)src;
        } else if constexpr (MODE == 1) {
            if (kc < 4) {
                qn = *(const uint4*)(io + (size_t)egc * 128 + kc * 32 + lg * 8);
            } else {
                const float* s = Fa + (size_t)egc * 128 + (kc - 4) * 32 + lg * 8;
                const float4 a = *(const float4*)s;
                const float4 b = *(const float4*)(s + 4);
                xn[0] = a.x; xn[1] = a.y; xn[2] = a.z; xn[3] = a.w;
                xn[4] = b.x; xn[5] = b.y; xn[6] = b.z; xn[7] = b.w;
            }
        }
    };

    const f32x4 zero4 = {0.f, 0.f, 0.f, 0.f};
    f32x4 acc[8];
    #pragma unroll
    for (int mf = 0; mf < 8; mf++) acc[mf] = zero4;

    prefetch(0);

    // ---------------- layer 1 (2-barrier K-step; unrolled, kc const) -----
    #pragma unroll
    for (int kc = 0; kc < NCH1; ++kc) {
        __syncthreads();                  // prior readers of WH done
        stage(W1h, K1S, kc);
        const bool isF16 = (MODE == 0) || (MODE == 1 && kc < 4);
        f16x8 XHv, XLv;
        bool useXL = false;
        if constexpr (MODE == 2) {
            union { f16 h[8]; f16x8 v; } uh, ul;
            #pragma unroll
            for (int j = 0; j < 8; j++) {
                const float x = (lg == 0) ? feat[j] : 0.f;
                const f16 h = (f16)x;
                uh.h[j] = h;
                ul.h[j] = (f16)(x - (float)h);
            }
            XHv = uh.v; XLv = ul.v; useXL = true;
        } else if (isF16) {
            union { uint4 q; f16x8 v; } cc; cc.q = qn;
            XHv = cc.v;
        } else {
            union { f16 h[8]; f16x8 v; } uh, ul;
            #pragma unroll
            for (int j = 0; j < 8; j++) {
                const f16 h = (f16)xn[j];
                uh.h[j] = h;
                ul.h[j] = (f16)(xn[j] - (float)h);   // unscaled lo: exact sum
            }
            XHv = uh.v; XLv = ul.v; useXL = true;
        }
        __syncthreads();                  // weights staged (vmcnt drained)
        if (kc + 1 < NCH1) prefetch(kc + 1);
        #pragma unroll
        for (int mf = 0; mf < 8; mf++) {
            const int off = (mf * 16 + lr) * 64 + (swz << 4);
            const f16x8 wh = *(const f16x8*)((const char*)WH + off);
            acc[mf] = __builtin_amdgcn_mfma_f32_16x16x32_f16(XHv, wh, acc[mf], 0, 0, 0);
            if (useXL)
                acc[mf] = __builtin_amdgcn_mfma_f32_16x16x32_f16(XLv, wh, acc[mf], 0, 0, 0);
        }
    }

    // layer-1 epilogue: bias+relu -> f16 Y at XOR-swizzled addr (r9-verified).
    #pragma unroll
    for (int mf = 0; mf < 8; mf++) {
        const float bb1 = b1[mf * 16 + lr];
        #pragma unroll
        for (int reg = 0; reg < 4; reg++) {
            float v = acc[mf][reg] + bb1;
            v = fmaxf(v, 0.f);
            union { f16 h; unsigned short u; } cc; cc.h = (f16)v;
            const int row = w * 16 + lg * 4 + reg;
            const int cb  = (mf * 16 + lr) * 2;
            *(unsigned short*)((char*)Yh + row * 256 +
                               (cb ^ (((lg * 4 + reg) & 7) << 4))) = cc.u;
        }
        acc[mf] = zero4;
    }

    // ---------------- layer 2 (f16 Y exact -> 1 MFMA per mf) ----------
    #pragma unroll
    for (int kc = 0; kc < 4; ++kc) {
        __syncthreads();                  // prior readers of WH done
        stage(W2h, 128, kc);
        union { uint4 q; f16x8 v; } YH;
        {
            const int row = w * 16 + lr;
            const int cb  = (kc * 32 + lg * 8) * 2;
            YH.q = *(const uint4*)((const char*)Yh + row * 256 +
                                   (cb ^ ((lr & 7) << 4)));
        }
        __syncthreads();                  // weights staged
        #pragma unroll
        for (int mf = 0; mf < 8; mf++) {
            const int off = (mf * 16 + lr) * 64 + (swz << 4);
            const f16x8 wh = *(const f16x8*)((const char*)WH + off);
            acc[mf] = __builtin_amdgcn_mfma_f32_16x16x32_f16(YH.v, wh, acc[mf], 0, 0, 0);
        }
    }

    // layer-2 epilogue (r5-verified): bias+relu+LN+apply+store (f16 io).
    float vv[8][4];
    float s1[4] = {0, 0, 0, 0}, s2[4] = {0, 0, 0, 0};
    #pragma unroll
    for (int mf = 0; mf < 8; mf++) {
        const float bb2 = b2[mf * 16 + lr];
        #pragma unroll
        for (int reg = 0; reg < 4; reg++) {
            float v = acc[mf][reg] + bb2;
            v = fmaxf(v, 0.f);
            vv[mf][reg] = v;
            s1[reg] += v; s2[reg] += v * v;
        }
    }
    #pragma unroll
    for (int m = 1; m < 16; m <<= 1) {
        #pragma unroll
        for (int reg = 0; reg < 4; reg++) {
            s1[reg] += __shfl_xor(s1[reg], m);
            s2[reg] += __shfl_xor(s2[reg], m);
        }
    }
    float gg[8], b8[8];
    #pragma unroll
    for (int mf = 0; mf < 8; mf++) {
        gg[mf] = gam[mf * 16 + lr];
        b8[mf] = bet[mf * 16 + lr];
    }

    #pragma unroll
    for (int reg = 0; reg < 4; reg++) {
        const float mu = s1[reg] * (1.f / 128.f);
        const float rs = rsqrtf(fmaxf(s2[reg] * (1.f / 128.f) - mu * mu, 0.f) + 1e-5f);
        const int row = w * 16 + lg * 4 + reg;
        const int idx = base + row;
        if (idx < nrows) {
            if constexpr (MODE == 0) {
                const int rc = receivers[idx];
                #pragma unroll
                for (int mf = 0; mf < 8; mf++) {
                    const int col = mf * 16 + lr;
                    const float o = gg[mf] * (vv[mf][reg] - mu) * rs + b8[mf];
                    atomicAdd(&aggr[(size_t)rc * 128 + col], o);       // segsum
                    f16* p = io + (size_t)idx * 128 + col;             // el res
                    *p = (f16)((float)*p + o);
                }
            } else if constexpr (MODE == 1) {
                #pragma unroll
                for (int mf = 0; mf < 8; mf++) {
                    const int col = mf * 16 + lr;
                    const float o = gg[mf] * (vv[mf][reg] - mu) * rs + b8[mf];
                    f16* p = io + (size_t)idx * 128 + col;             // nl res
                    *p = (f16)((float)*p + o);
                }
            } else {
                #pragma unroll
                for (int mf = 0; mf < 8; mf++) {
                    const int col = mf * 16 + lr;
                    const float o = gg[mf] * (vv[mf][reg] - mu) * rs + b8[mf];
                    io[(size_t)idx * 128 + col] = (f16)o;              // el enc
                }
            }
        }
    }
}

// Decoder -> FLOAT32 output, layout [TW, N, TD]. Reads f16 nl.
__global__ __launch_bounds__(128) void decode_k(
    const f16* __restrict__ nl,
    const float* __restrict__ W1, const float* __restrict__ b1,
    const float* __restrict__ W2, const float* __restrict__ b2,
    float* __restrict__ out)
{
    constexpr int NPB = 16;
    __shared__ __align__(16) float xs[NPB * LNUM];
    __shared__ float hh[NPB * 8];
    const int t = threadIdx.x;
    const int base = blockIdx.x * NPB;
    for (int r = 0; r < NPB; r++) xs[r * LNUM + t] = (float)nl[(base + r) * LNUM + t];
    __syncthreads();
    {
        const int node = t >> 3, j = t & 7;
        float a = b1[j];
        for (int k = 0; k < LNUM; k++) a = fmaf(xs[node * LNUM + k], W1[k * 8 + j], a);
        hh[node * 8 + j] = a / (1.f + expf(-a));
    }
    __syncthreads();
    for (int idx = t; idx < NPB * 10; idx += 128) {
        const int node = idx / 10, c = idx % 10;
        float a = b2[c];
        #pragma unroll
        for (int j = 0; j < 8; j++) a = fmaf(hh[node * 8 + j], W2[j * 10 + c], a);
        const int tt = c >> 1, d = c & 1;
        out[(size_t)tt * (NNODES * 2) + (size_t)(base + node) * 2 + d] =
            a * (float)(tt + 1);
    }
}

__global__ __launch_bounds__(256) void zero_k(float* __restrict__ p, int n)
{
    const int i = blockIdx.x * 256 + threadIdx.x;
    if (i < n) p[i] = 0.f;
}

// ---------------------------------------------------------------------------
extern "C" void kernel_launch(void* const* d_in, const int* in_sizes, int n_in,
                              void* d_out, int out_size, void* d_ws, size_t ws_size,
                              hipStream_t stream) {
    const float* F[34];
    for (int i = 0; i < 34; i++) F[i] = (const float*)d_in[i];
    const int* senders   = (const int*)d_in[4];
    const int* receivers = (const int*)d_in[5];

    const size_t nN = (size_t)NNODES * LNUM;
    const size_t nE = (size_t)NEDGES * LNUM;
    f16* nl16 = (f16*)d_ws;                 // 7.68 MB
    f16* el16 = nl16 + nN;                  // 38.4 MB
    float* aggr = (float*)(el16 + nE);      // 15.36 MB
    f16* wb = (f16*)(aggr + nN);
    f16 *eW1h = wb;
    f16 *eW2h = eW1h + PE1;
    f16 *nW1h = eW2h + PE2;
    f16 *nW2h = nW1h + PN1;
    f16 *qW1h = nW2h + PN2;
    f16 *qW2h = qW1h + PQ1;

    prep_w_all_k<<<(PTOT + 255) / 256, 256, 0, stream>>>(
        F[18], F[20], F[24], F[26], F[12], F[14], wb);

    encode_nodes_k<<<NNODES / 4, 128, 0, stream>>>(
        F[2], F[3], F[1], F[6], F[7], F[8], F[9], F[10], F[11], nl16);

    const int egrid = (NEDGES + 63) / 64;   // 2344 blocks of 256 threads
    const int ngrid = (NNODES + 63) / 64;   // 469

    // edge encoder (MFMA, computed f32 features -> f16 el)
    mfma_mlp_k<2, 1, 32><<<egrid, 256, 0, stream>>>(
        nullptr, F[0], F[2], el16, nullptr, senders, receivers,
        qW1h, F[13], qW2h, F[15], F[16], F[17], NEDGES);

    for (int s = 0; s < NSTEPS; s++) {
        zero_k<<<(NNODES * LNUM + 255) / 256, 256, 0, stream>>>(aggr, NNODES * LNUM);
        mfma_mlp_k<0, 12, 384><<<egrid, 256, 0, stream>>>(
            nl16, nullptr, nullptr, el16, aggr, senders, receivers,
            eW1h + (size_t)s * 384 * 128, F[19] + s * LNUM,
            eW2h + (size_t)s * 128 * 128, F[21] + s * LNUM,
            F[22] + s * LNUM, F[23] + s * LNUM, NEDGES);
        mfma_mlp_k<1, 8, 256><<<ngrid, 256, 0, stream>>>(
            nullptr, aggr, nullptr, nl16, nullptr, nullptr, nullptr,
            nW1h + (size_t)s * 256 * 128, F[25] + s * LNUM,
            nW2h + (size_t)s * 128 * 128, F[27] + s * LNUM,
            F[28] + s * LNUM, F[29] + s * LNUM, NNODES);
    }

    decode_k<<<NNODES / 16, 128, 0, stream>>>(
        nl16, F[30], F[31], F[32], F[33], (float*)d_out);
}

// Round 11
// 787.102 us; speedup vs baseline: 1.9815x; 1.0084x over previous
//
#include <hip/hip_runtime.h>
#include <hip/hip_bf16.h>

#define LNUM 128
#define NNODES 30000
#define NEDGES 150000
#define NSTEPS 5

// NOTE (r17 discovery): d_out is FLOAT32 (reference is pure jnp.float32).
// r10 post-mortem: 794us; edge 100us traffic-bound, largest stream = f32
// atomic aggregation (76.8MB write-through + RMW). r11: aggr stored f16,
// scattered via packed global_atomic_pk_add_f16 (even lanes, pair via
// shfl_xor(1)): atomic bytes halve, zero halves, node kernel reads f16 aggr
// EXACTLY (single MFMA, f32 split path gone). CAS fallback if no builtin.

typedef _Float16 f16;
typedef __attribute__((ext_vector_type(2))) _Float16 f16x2;
typedef __attribute__((ext_vector_type(8))) _Float16 f16x8;
typedef __attribute__((ext_vector_type(4))) float f32x4;

__device__ __forceinline__ void glds16(const void* g, void* l) {
    __builtin_amdgcn_global_load_lds(
        (const __attribute__((address_space(1))) void*)g,
        (__attribute__((address_space(3))) void*)l, 16, 0, 0);
}

__device__ __forceinline__ void atomic_pk_add(f16* addr, f16 lo, f16 hi) {
#if __has_builtin(__builtin_amdgcn_global_atomic_fadd_v2f16)
    f16x2 v; v[0] = lo; v[1] = hi;
    __builtin_amdgcn_global_atomic_fadd_v2f16(
        (__attribute__((address_space(1))) f16x2*)addr, v);
#else
    uint32_t* p = (uint32_t*)addr;
    uint32_t old = *p, assumed;
    do {
        assumed = old;
        union { uint32_t u; f16 h[2]; } c; c.u = assumed;
        c.h[0] += lo; c.h[1] += hi;
        old = atomicCAS(p, assumed, c.u);
    } while (old != assumed);
#endif
}

// ---------------------------------------------------------------------------
// Legacy VALU MLP core: still used by the (small) encode_nodes kernel.
// ---------------------------------------------------------------------------
template<int ROWS, int K, int KP>
__device__ __forceinline__ void mlp_apply(
    const float* __restrict__ xs, float* __restrict__ hv,
    float* __restrict__ mu_s, float* __restrict__ rs_s,
    const float* __restrict__ W1, const float* __restrict__ b1,
    const float* __restrict__ W2, const float* __restrict__ b2,
    const float* __restrict__ g,  const float* __restrict__ be,
    float out[ROWS])
{
    const int t = threadIdx.x;
    float acc[ROWS];
    {
        const float bb = b1[t];
        #pragma unroll
        for (int r = 0; r < ROWS; r++) acc[r] = bb;
    }
    int k = 0;
    for (; k + 4 <= K; k += 4) {
        const float w0 = W1[(k + 0) * LNUM + t];
        const float w1 = W1[(k + 1) * LNUM + t];
        const float w2 = W1[(k + 2) * LNUM + t];
        const float w3 = W1[(k + 3) * LNUM + t];
        #pragma unroll
        for (int r = 0; r < ROWS; r++) {
            const float4 x = *(const float4*)(xs + r * KP + k);
            acc[r] = fmaf(x.x, w0, acc[r]);
            acc[r] = fmaf(x.y, w1, acc[r]);
            acc[r] = fmaf(x.z, w2, acc[r]);
            acc[r] = fmaf(x.w, w3, acc[r]);
        }
    }
    for (; k < K; ++k) {
        const float w = W1[k * LNUM + t];
        #pragma unroll
        for (int r = 0; r < ROWS; r++) acc[r] = fmaf(xs[r * KP + k], w, acc[r]);
    }
    #pragma unroll
    for (int r = 0; r < ROWS; r++) hv[r * LNUM + t] = fmaxf(acc[r], 0.f);
    __syncthreads();
    {
        const float bb = b2[t];
        #pragma unroll
        for (int r = 0; r < ROWS; r++) acc[r] = bb;
    }
    for (int k2 = 0; k2 < LNUM; k2 += 4) {
        const float w0 = W2[(k2 + 0) * LNUM + t];
        const float w1 = W2[(k2 + 1) * LNUM + t];
        const float w2 = W2[(k2 + 2) * LNUM + t];
        const float w3 = W2[(k2 + 3) * LNUM + t];
        #pragma unroll
        for (int r = 0; r < ROWS; r++) {
            const float4 x = *(const float4*)(hv + r * LNUM + k2);
            acc[r] = fmaf(x.x, w0, acc[r]);
            acc[r] = fmaf(x.y, w1, acc[r]);
            acc[r] = fmaf(x.z, w2, acc[r]);
            acc[r] = fmaf(x.w, w3, acc[r]);
        }
    }
    __syncthreads();
    #pragma unroll
    for (int r = 0; r < ROWS; r++) hv[r * LNUM + t] = fmaxf(acc[r], 0.f);
    __syncthreads();
    if (t < ROWS) {
        float s = 0.f, s2 = 0.f;
        for (int kk = 0; kk < LNUM; kk++) {
            const float v = hv[t * LNUM + kk];
            s += v; s2 += v * v;
        }
        const float m = s * (1.0f / LNUM);
        mu_s[t] = m;
        rs_s[t] = rsqrtf(fmaxf(s2 * (1.0f / LNUM) - m * m, 0.f) + 1e-5f);
    }
    __syncthreads();
    const float gg = g[t], bbe = be[t];
    #pragma unroll
    for (int r = 0; r < ROWS; r++)
        out[r] = fmaf(gg * (hv[r * LNUM + t] - mu_s[r]), rs_s[r], bbe);
}

__global__ __launch_bounds__(128) void encode_nodes_k(
    const float* __restrict__ u, const float* __restrict__ load_,
    const float* __restrict__ ntype,
    const float* __restrict__ W1, const float* __restrict__ b1,
    const float* __restrict__ W2, const float* __restrict__ b2,
    const float* __restrict__ g,  const float* __restrict__ be,
    f16* __restrict__ nl)
{
    constexpr int ROWS = 4, K = 12, KP = 12;
    __shared__ __align__(16) float xs[ROWS * KP];
    __shared__ __align__(16) float hv[ROWS * LNUM];
    __shared__ float mu_s[ROWS], rs_s[ROWS];
    const int t = threadIdx.x;
    const int base = blockIdx.x * ROWS;
    if (t < ROWS * K) {
        const int r = t / K, k = t % K;
        const int n = base + r;
        float v;
        if (k < 2)      v = u[n * 2 + k];
        else if (k < 3) v = load_[n];
        else            v = ntype[n * 9 + (k - 3)];
        xs[r * KP + k] = v;
    }
    __syncthreads();
    float out[ROWS];
    mlp_apply<ROWS, K, KP>(xs, hv, mu_s, rs_s, W1, b1, W2, b2, g, be, out);
    #pragma unroll
    for (int r = 0; r < ROWS; r++) nl[(base + r) * LNUM + t] = (f16)out[r];
}

// ---------------------------------------------------------------------------
// Weight prep: f32 [S][K][128] -> f16 hi tables transposed to [S][128][K].
// ---------------------------------------------------------------------------
#define PE1 245760   // 5*384*128 (edge W1)
#define PE2 81920    // 5*128*128 (edge W2)
#define PN1 163840   // 5*256*128 (node W1)
#define PN2 81920    // 5*128*128 (node W2)
#define PQ1 4096     // 128*32    (enc-edge W1, k-padded)
#define PQ2 16384    // 128*128   (enc-edge W2)
#define PTOT (PE1+PE2+PN1+PN2+PQ1+PQ2)

__global__ __launch_bounds__(256) void prep_w_all_k(
    const float* __restrict__ eW1, const float* __restrict__ eW2,
    const float* __restrict__ nW1, const float* __restrict__ nW2,
    const float* __restrict__ qW1, const float* __restrict__ qW2,
    f16* __restrict__ out)
{
    int j = blockIdx.x * 256 + threadIdx.x;
    if (j >= PTOT) return;
    const float* W; int K, kreal; f16* hi; f16* p = out;
    if (j < PE1) { W = eW1; K = 384; kreal = 384; hi = p; }
    else { p += PE1; j -= PE1;
    if (j < PE2) { W = eW2; K = 128; kreal = 128; hi = p; }
    else { p += PE2; j -= PE2;
    if (j < PN1) { W = nW1; K = 256; kreal = 256; hi = p; }
    else { p += PN1; j -= PN1;
    if (j < PN2) { W = nW2; K = 128; kreal = 128; hi = p; }
    else { p += PN2; j -= PN2;
    if (j < PQ1) { W = qW1; K = 32;  kreal = 5;   hi = p; }
    else { p += PQ1; j -= PQ1;
         { W = qW2; K = 128; kreal = 128; hi = p; } } } } } }
    const int k = j % K;
    const int rem = j / K;
    const int n = rem & 127;
    const int s = rem >> 7;
    const float v = (k < kreal) ? W[((size_t)s * kreal + k) * 128 + n] : 0.f;
    hi[j] = (f16)v;
}

// ---------------------------------------------------------------------------
// MFMA MLP, f16 weights + f16 latents + f16 aggr. 256 thr, 64 rows/block.
// Weights: ONE 32-wide K chunk (8KB) staged per iter (r5-verified glds16 +
// XOR swizzle, 2 barriers/chunk). f16 data chunks are EXACT: single MFMA/mf.
// MODE2 f32 features use the unscaled-lo split (2 MFMA/mf).
// Layer1->2 via f16-only Y in 16KB XOR-swizzled LDS (r9-verified).
// D layout (verified): edge = w*16+lg*4+reg, feature = mf*16+lr.
// MODE: 0 = edge block (Lat=nl16, io=el16 RMW, aggr16 pk-atomics)
//       1 = node block (Lat=aggr16, io=nl16 RMW)
//       2 = edge encoder (Fa=mesh_pos, Fb=u, io=el16 store)
// ---------------------------------------------------------------------------
template<int MODE, int NCH1, int K1S>
__global__ __launch_bounds__(256, 6) void mfma_mlp_k(
    const f16* __restrict__ Lat, const float* __restrict__ Fa,
    const float* __restrict__ Fb,
    f16* __restrict__ io, f16* __restrict__ aggr,
    const int* __restrict__ senders, const int* __restrict__ receivers,
    const f16* __restrict__ W1h, const float* __restrict__ b1,
    const f16* __restrict__ W2h, const float* __restrict__ b2,
    const float* __restrict__ gam, const float* __restrict__ bet,
    int nrows)
{
    __shared__ __align__(16) f16 WH[4096];                 // [128][32] swz, 8KB
    __shared__ __align__(16) unsigned short Yh[64 * 128];  // f16, swizzled, 16KB

    const int t  = threadIdx.x;
    const int w  = t >> 6;
    const int l  = t & 63;
    const int lr = l & 15;
    const int lg = l >> 4;
    const int swz = lg ^ ((lr >> 1) & 3);
    const int base = blockIdx.x * 64;

    const int eg  = base + w * 16 + lr;    // this lane's gather row (A-row)
    const int egc = min(eg, nrows - 1);

    int sv = 0, rv = 0;
    if constexpr (MODE != 1) { sv = senders[egc]; rv = receivers[egc]; }

    float feat[8];
    if constexpr (MODE == 2) {
        const float ax = Fa[sv * 2], ay = Fa[sv * 2 + 1];
        const float bx = Fa[rv * 2], by = Fa[rv * 2 + 1];
        const float rx = ax - bx, ry = ay - by;
        feat[0] = rx; feat[1] = ry; feat[2] = sqrtf(rx * rx + ry * ry);
        feat[3] = Fb[sv * 2] - Fb[rv * 2];
        feat[4] = Fb[sv * 2 + 1] - Fb[rv * 2 + 1];
        feat[5] = 0.f; feat[6] = 0.f; feat[7] = 0.f;
    }

    // r5-verified cooperative stage of one 32-wide K chunk.
    auto stage = [&](const f16* __restrict__ Wh, const int kst, const int kc) {
        #pragma unroll
        for (int i = 0; i < 2; i++) {
            const int c = 2 * w + i;
            const int ophys = c * 1024 + l * 16;
            const int olog  = ophys ^ (((ophys >> 7) & 3) << 4);
            const int row   = olog >> 6;
            const int slot  = (olog >> 4) & 3;
            glds16(Wh + (size_t)row * kst + kc * 32 + slot * 8, (char*)WH + c * 1024);
        }
    };

    uint4 qn;   // f16 chunk prefetch register
    auto prefetch = [&](int kc) {
        if constexpr (MODE == 0) {
            const f16* src;
            if (kc < 4)      src = Lat + (size_t)sv  * 128 + kc * 32 + lg * 8;
            else if (kc < 8) src = Lat + (size_t)rv  * 128 + (kc - 4) * 32 + lg * 8;
            else             src = io  + (size_t)egc * 128 + (kc - 8) * 32 + lg * 8;
            qn = *(const uint4*)src;
        } else if constexpr (MODE == 1) {
            const f16* src;
            if (kc < 4) src = io  + (size_t)egc * 128 + kc * 32 + lg * 8;
            else        src = Lat + (size_t)egc * 128 + (kc - 4) * 32 + lg * 8;
            qn = *(const uint4*)src;
        }
    };

    const f32x4 zero4 = {0.f, 0.f, 0.f, 0.f};
    f32x4 acc[8];
    #pragma unroll
    for (int mf = 0; mf < 8; mf++) acc[mf] = zero4;

    prefetch(0);

    // ---------------- layer 1 (2-barrier K-step) ----------------
    #pragma unroll
    for (int kc = 0; kc < NCH1; ++kc) {
        __syncthreads();                  // prior readers of WH done
        stage(W1h, K1S, kc);
        f16x8 XHv, XLv;
        bool useXL = false;
        if constexpr (MODE == 2) {
            union { f16 h[8]; f16x8 v; } uh, ul;
            #pragma unroll
            for (int j = 0; j < 8; j++) {
                const float x = (lg == 0) ? feat[j] : 0.f;
                const f16 h = (f16)x;
                uh.h[j] = h;
                ul.h[j] = (f16)(x - (float)h);   // unscaled lo: exact sum
            }
            XHv = uh.v; XLv = ul.v; useXL = true;
        } else {
            union { uint4 q; f16x8 v; } cc; cc.q = qn;
            XHv = cc.v;
        }
        __syncthreads();                  // weights staged (vmcnt drained)
        if (kc + 1 < NCH1) prefetch(kc + 1);
        #pragma unroll
        for (int mf = 0; mf < 8; mf++) {
            const int off = (mf * 16 + lr) * 64 + (swz << 4);
            const f16x8 wh = *(const f16x8*)((const char*)WH + off);
            acc[mf] = __builtin_amdgcn_mfma_f32_16x16x32_f16(XHv, wh, acc[mf], 0, 0, 0);
            if (useXL)
                acc[mf] = __builtin_amdgcn_mfma_f32_16x16x32_f16(XLv, wh, acc[mf], 0, 0, 0);
        }
    }

    // layer-1 epilogue: bias+relu -> f16 Y at XOR-swizzled addr (r9-verified).
    #pragma unroll
    for (int mf = 0; mf < 8; mf++) {
        const float bb1 = b1[mf * 16 + lr];
        #pragma unroll
        for (int reg = 0; reg < 4; reg++) {
            float v = acc[mf][reg] + bb1;
            v = fmaxf(v, 0.f);
            union { f16 h; unsigned short u; } cc; cc.h = (f16)v;
            const int row = w * 16 + lg * 4 + reg;
            const int cb  = (mf * 16 + lr) * 2;
            *(unsigned short*)((char*)Yh + row * 256 +
                               (cb ^ (((lg * 4 + reg) & 7) << 4))) = cc.u;
        }
        acc[mf] = zero4;
    }

    // ---------------- layer 2 (f16 Y exact -> 1 MFMA per mf) ----------
    #pragma unroll
    for (int kc = 0; kc < 4; ++kc) {
        __syncthreads();                  // prior readers of WH done
        stage(W2h, 128, kc);
        union { uint4 q; f16x8 v; } YH;
        {
            const int row = w * 16 + lr;
            const int cb  = (kc * 32 + lg * 8) * 2;
            YH.q = *(const uint4*)((const char*)Yh + row * 256 +
                                   (cb ^ ((lr & 7) << 4)));
        }
        __syncthreads();                  // weights staged
        #pragma unroll
        for (int mf = 0; mf < 8; mf++) {
            const int off = (mf * 16 + lr) * 64 + (swz << 4);
            const f16x8 wh = *(const f16x8*)((const char*)WH + off);
            acc[mf] = __builtin_amdgcn_mfma_f32_16x16x32_f16(YH.v, wh, acc[mf], 0, 0, 0);
        }
    }

    // layer-2 epilogue (r5-verified): bias+relu+LN+apply+store (f16 io).
    float vv[8][4];
    float s1[4] = {0, 0, 0, 0}, s2[4] = {0, 0, 0, 0};
    #pragma unroll
    for (int mf = 0; mf < 8; mf++) {
        const float bb2 = b2[mf * 16 + lr];
        #pragma unroll
        for (int reg = 0; reg < 4; reg++) {
            float v = acc[mf][reg] + bb2;
            v = fmaxf(v, 0.f);
            vv[mf][reg] = v;
            s1[reg] += v; s2[reg] += v * v;
        }
    }
    #pragma unroll
    for (int m = 1; m < 16; m <<= 1) {
        #pragma unroll
        for (int reg = 0; reg < 4; reg++) {
            s1[reg] += __shfl_xor(s1[reg], m);
            s2[reg] += __shfl_xor(s2[reg], m);
        }
    }
    float gg[8], b8[8];
    #pragma unroll
    for (int mf = 0; mf < 8; mf++) {
        gg[mf] = gam[mf * 16 + lr];
        b8[mf] = bet[mf * 16 + lr];
    }

    #pragma unroll
    for (int reg = 0; reg < 4; reg++) {
        const float mu = s1[reg] * (1.f / 128.f);
        const float rs = rsqrtf(fmaxf(s2[reg] * (1.f / 128.f) - mu * mu, 0.f) + 1e-5f);
        const int row = w * 16 + lg * 4 + reg;
        const int idx = base + row;
        if (idx < nrows) {
            if constexpr (MODE == 0) {
                const int rc = receivers[idx];   // uniform across lr-group
                #pragma unroll
                for (int mf = 0; mf < 8; mf++) {
                    const int col = mf * 16 + lr;
                    const float o = gg[mf] * (vv[mf][reg] - mu) * rs + b8[mf];
                    // packed f16 atomic: even lane covers cols (c, c+1)
                    const float op = __shfl_xor(o, 1);
                    if ((lr & 1) == 0)
                        atomic_pk_add(aggr + (size_t)rc * 128 + col,
                                      (f16)o, (f16)op);            // segsum
                    f16* p = io + (size_t)idx * 128 + col;         // el res
                    *p = (f16)((float)*p + o);
                }
            } else if constexpr (MODE == 1) {
                #pragma unroll
                for (int mf = 0; mf < 8; mf++) {
                    const int col = mf * 16 + lr;
                    const float o = gg[mf] * (vv[mf][reg] - mu) * rs + b8[mf];
                    f16* p = io + (size_t)idx * 128 + col;         // nl res
                    *p = (f16)((float)*p + o);
                }
            } else {
                #pragma unroll
                for (int mf = 0; mf < 8; mf++) {
                    const int col = mf * 16 + lr;
                    const float o = gg[mf] * (vv[mf][reg] - mu) * rs + b8[mf];
                    io[(size_t)idx * 128 + col] = (f16)o;          // el enc
                }
            }
        }
    }
}

// Decoder -> FLOAT32 output, layout [TW, N, TD]. Reads f16 nl.
__global__ __launch_bounds__(128) void decode_k(
    const f16* __restrict__ nl,
    const float* __restrict__ W1, const float* __restrict__ b1,
    const float* __restrict__ W2, const float* __restrict__ b2,
    float* __restrict__ out)
{
    constexpr int NPB = 16;
    __shared__ __align__(16) float xs[NPB * LNUM];
    __shared__ float hh[NPB * 8];
    const int t = threadIdx.x;
    const int base = blockIdx.x * NPB;
    for (int r = 0; r < NPB; r++) xs[r * LNUM + t] = (float)nl[(base + r) * LNUM + t];
    __syncthreads();
    {
        const int node = t >> 3, j = t & 7;
        float a = b1[j];
        for (int k = 0; k < LNUM; k++) a = fmaf(xs[node * LNUM + k], W1[k * 8 + j], a);
        hh[node * 8 + j] = a / (1.f + expf(-a));
    }
    __syncthreads();
    for (int idx = t; idx < NPB * 10; idx += 128) {
        const int node = idx / 10, c = idx % 10;
        float a = b2[c];
        #pragma unroll
        for (int j = 0; j < 8; j++) a = fmaf(hh[node * 8 + j], W2[j * 10 + c], a);
        const int tt = c >> 1, d = c & 1;
        out[(size_t)tt * (NNODES * 2) + (size_t)(base + node) * 2 + d] =
            a * (float)(tt + 1);
    }
}

__global__ __launch_bounds__(256) void zero_k(float* __restrict__ p, int n)
{
    const int i = blockIdx.x * 256 + threadIdx.x;
    if (i < n) p[i] = 0.f;
}

// ---------------------------------------------------------------------------
extern "C" void kernel_launch(void* const* d_in, const int* in_sizes, int n_in,
                              void* d_out, int out_size, void* d_ws, size_t ws_size,
                              hipStream_t stream) {
    const float* F[34];
    for (int i = 0; i < 34; i++) F[i] = (const float*)d_in[i];
    const int* senders   = (const int*)d_in[4];
    const int* receivers = (const int*)d_in[5];

    const size_t nN = (size_t)NNODES * LNUM;
    const size_t nE = (size_t)NEDGES * LNUM;
    f16* nl16   = (f16*)d_ws;               // 7.68 MB
    f16* el16   = nl16 + nN;                // 38.4 MB
    f16* aggr16 = el16 + nE;                // 7.68 MB
    f16* wb     = aggr16 + nN;
    f16 *eW1h = wb;
    f16 *eW2h = eW1h + PE1;
    f16 *nW1h = eW2h + PE2;
    f16 *nW2h = nW1h + PN1;
    f16 *qW1h = nW2h + PN2;
    f16 *qW2h = qW1h + PQ1;

    prep_w_all_k<<<(PTOT + 255) / 256, 256, 0, stream>>>(
        F[18], F[20], F[24], F[26], F[12], F[14], wb);

    encode_nodes_k<<<NNODES / 4, 128, 0, stream>>>(
        F[2], F[3], F[1], F[6], F[7], F[8], F[9], F[10], F[11], nl16);

    const int egrid = (NEDGES + 63) / 64;   // 2344 blocks of 256 threads
    const int ngrid = (NNODES + 63) / 64;   // 469

    // edge encoder (MFMA, computed f32 features -> f16 el)
    mfma_mlp_k<2, 1, 32><<<egrid, 256, 0, stream>>>(
        nullptr, F[0], F[2], el16, nullptr, senders, receivers,
        qW1h, F[13], qW2h, F[15], F[16], F[17], NEDGES);

    for (int s = 0; s < NSTEPS; s++) {
        // zero f16 aggr (7.68MB) via f32-typed stores
        zero_k<<<(NNODES * 64 + 255) / 256, 256, 0, stream>>>(
            (float*)aggr16, NNODES * 64);
        mfma_mlp_k<0, 12, 384><<<egrid, 256, 0, stream>>>(
            nl16, nullptr, nullptr, el16, aggr16, senders, receivers,
            eW1h + (size_t)s * 384 * 128, F[19] + s * LNUM,
            eW2h + (size_t)s * 128 * 128, F[21] + s * LNUM,
            F[22] + s * LNUM, F[23] + s * LNUM, NEDGES);
        mfma_mlp_k<1, 8, 256><<<ngrid, 256, 0, stream>>>(
            aggr16, nullptr, nullptr, nl16, nullptr, nullptr, nullptr,
            nW1h + (size_t)s * 256 * 128, F[25] + s * LNUM,
            nW2h + (size_t)s * 128 * 128, F[27] + s * LNUM,
            F[28] + s * LNUM, F[29] + s * LNUM, NNODES);
    }

    decode_k<<<NNODES / 16, 128, 0, stream>>>(
        nl16, F[30], F[31], F[32], F[33], (float*)d_out);
}